// Round 1
// baseline (4183.871 us; speedup 1.0000x reference)
//
#include <hip/hip_runtime.h>
#include <math.h>

#define H 512
#define V 128
#define NLEAF 16384

// ---- static device scratch (~100.7 MB): ping-pong h/c + small vectors ----
__device__ float g_h0[NLEAF * H];        // levels 14,12,10,...,0
__device__ float g_c0[NLEAF * H];
__device__ float g_h1[(NLEAF / 2) * H];  // levels 13,11,...,1
__device__ float g_c1[(NLEAF / 2) * H];
__device__ float g_root[2 * H];          // h_root | c_root
__device__ float g_hf[H];
__device__ float g_gates[4 * H];

__device__ __forceinline__ float sigm(float x) { return 1.0f / (1.0f + __expf(-x)); }
__device__ __forceinline__ float ftanh(float x) {
  // tanh(x) = 1 - 2/(exp(2x)+1); saturates correctly for large |x|
  return 1.0f - 2.0f / (__expf(2.0f * x) + 1.0f);
}

// ---------------- leaf level (lvl 14): hk = ck = 0, pure elementwise -------
__global__ __launch_bounds__(256) void k_leaf(const int* __restrict__ tokens,
                                              const float* __restrict__ Wiou,
                                              const float* __restrict__ biou) {
  int idx = blockIdx.x * 256 + threadIdx.x;          // 0 .. NLEAF*H
  int i = idx >> 9, j = idx & (H - 1);
  int tok = tokens[(NLEAF - 1) + i];
  const float* Wr = Wiou + tok * 3 * H;
  float ig = Wr[j] + biou[j];
  float og = Wr[H + j] + biou[H + j];
  float ug = Wr[2 * H + j] + biou[2 * H + j];
  float c = sigm(ig) * ftanh(ug);
  float h = sigm(og) * ftanh(c);
  g_h0[idx] = h;
  g_c0[idx] = c;
}

// ---------------- big levels (n >= 64): tiled fused cell -------------------
// block: 512 thr = 64 col-threads x 8 node-threads; tile 64 nodes x 64 cols
__global__ __launch_bounds__(512) void k_cell_big(int lvl,
    const int* __restrict__ tokens,
    const float* __restrict__ Uiou,   // (1024,1536)
    const float* __restrict__ Uf,     // (2,512,512)
    const float* __restrict__ Wiou, const float* __restrict__ biou,
    const float* __restrict__ Wf, const float* __restrict__ bf) {
  const int n = 1 << lvl;
  const int node0 = n - 1;
  const int outp = lvl & 1;  // 1 -> write buf1 (odd levels), read buf0
  const float* __restrict__ hprev = outp ? g_h0 : g_h1;
  const float* __restrict__ cprev = outp ? g_c0 : g_c1;
  float* __restrict__ hout = outp ? g_h1 : g_h0;
  float* __restrict__ cout = outp ? g_c1 : g_c0;

  const int i0 = blockIdx.x * 64;
  const int tc = threadIdx.x & 63;
  const int nt = threadIdx.x >> 6;              // 0..7
  const int j = (blockIdx.y << 6) + tc;         // 0..511

  __shared__ float Hlds[64][32];

  float ai[8] = {0}, ao[8] = {0}, au[8] = {0}, af0[8] = {0}, af1[8] = {0};

  for (int kt = 0; kt < 2 * H; kt += 32) {
    __syncthreads();
    for (int r = threadIdx.x; r < 64 * 32; r += 512) {
      int nd = r >> 5, kk = r & 31;
      Hlds[nd][kk] = hprev[(size_t)(i0 + nd) * (2 * H) + kt + kk];
    }
    __syncthreads();
    const float* Up = Uiou + (size_t)kt * (3 * H) + j;
    const float* Ufp = Uf + ((kt < H) ? (size_t)kt * H
                                      : (size_t)(H * H) + (size_t)(kt - H) * H) + j;
    if (kt < H) {
      #pragma unroll 4
      for (int kk = 0; kk < 32; ++kk) {
        float wi = Up[kk * 1536];
        float wo = Up[kk * 1536 + 512];
        float wu = Up[kk * 1536 + 1024];
        float wf = Ufp[kk * 512];
        #pragma unroll
        for (int nd = 0; nd < 8; ++nd) {
          float a = Hlds[nt * 8 + nd][kk];
          ai[nd] += a * wi; ao[nd] += a * wo; au[nd] += a * wu; af0[nd] += a * wf;
        }
      }
    } else {
      #pragma unroll 4
      for (int kk = 0; kk < 32; ++kk) {
        float wi = Up[kk * 1536];
        float wo = Up[kk * 1536 + 512];
        float wu = Up[kk * 1536 + 1024];
        float wf = Ufp[kk * 512];
        #pragma unroll
        for (int nd = 0; nd < 8; ++nd) {
          float a = Hlds[nt * 8 + nd][kk];
          ai[nd] += a * wi; ao[nd] += a * wo; au[nd] += a * wu; af1[nd] += a * wf;
        }
      }
    }
  }

  float bi = biou[j], bo = biou[H + j], bu = biou[2 * H + j], bfv = bf[j];
  #pragma unroll
  for (int nd = 0; nd < 8; ++nd) {
    int i = i0 + nt * 8 + nd;
    int tok = tokens[node0 + i];
    const float* Wr = Wiou + tok * 3 * H;
    float fpre = Wf[tok * H + j] + bfv;
    float ig = ai[nd] + Wr[j] + bi;
    float og = ao[nd] + Wr[H + j] + bo;
    float ug = au[nd] + Wr[2 * H + j] + bu;
    float f0 = sigm(fpre + af0[nd]);
    float f1 = sigm(fpre + af1[nd]);
    float cc = sigm(ig) * ftanh(ug)
             + f0 * cprev[(size_t)(2 * i) * H + j]
             + f1 * cprev[(size_t)(2 * i + 1) * H + j];
    float hh = sigm(og) * ftanh(cc);
    hout[(size_t)i * H + j] = hh;
    cout[(size_t)i * H + j] = cc;
  }
}

// ---------------- small levels (n <= 32): latency-oriented, no LDS ---------
__global__ __launch_bounds__(512) void k_cell_small(int lvl,
    const int* __restrict__ tokens,
    const float* __restrict__ Uiou, const float* __restrict__ Uf,
    const float* __restrict__ Wiou, const float* __restrict__ biou,
    const float* __restrict__ Wf, const float* __restrict__ bf) {
  const int n = 1 << lvl;
  const int node0 = n - 1;
  const int outp = lvl & 1;
  const float* __restrict__ hprev = outp ? g_h0 : g_h1;
  const float* __restrict__ cprev = outp ? g_c0 : g_c1;
  float* __restrict__ hout = outp ? g_h1 : g_h0;
  float* __restrict__ cout = outp ? g_c1 : g_c0;

  const int tc = threadIdx.x & 63;
  const int nt = threadIdx.x >> 6;
  const int i = blockIdx.x * 8 + nt;
  const int j = (blockIdx.y << 6) + tc;
  if (i >= n) return;

  const float* hp = hprev + (size_t)i * (2 * H);
  float ai = 0, ao = 0, au = 0, af0 = 0, af1 = 0;
  for (int m = 0; m < H; ++m) {
    float a = hp[m];
    ai += a * Uiou[m * 1536 + j];
    ao += a * Uiou[m * 1536 + 512 + j];
    au += a * Uiou[m * 1536 + 1024 + j];
    af0 += a * Uf[m * H + j];
  }
  for (int m = H; m < 2 * H; ++m) {
    float a = hp[m];
    ai += a * Uiou[m * 1536 + j];
    ao += a * Uiou[m * 1536 + 512 + j];
    au += a * Uiou[m * 1536 + 1024 + j];
    af1 += a * Uf[H * H + (m - H) * H + j];
  }

  int tok = tokens[node0 + i];
  const float* Wr = Wiou + tok * 3 * H;
  float fpre = Wf[tok * H + j] + bf[j];
  float ig = ai + Wr[j] + biou[j];
  float og = ao + Wr[H + j] + biou[H + j];
  float ug = au + Wr[2 * H + j] + biou[2 * H + j];
  float f0 = sigm(fpre + af0);
  float f1 = sigm(fpre + af1);
  float cc = sigm(ig) * ftanh(ug)
           + f0 * cprev[(size_t)(2 * i) * H + j]
           + f1 * cprev[(size_t)(2 * i + 1) * H + j];
  float hh = sigm(og) * ftanh(cc);
  hout[(size_t)i * H + j] = hh;
  cout[(size_t)i * H + j] = cc;
}

// ---------------- root ternary cell ---------------------------------------
__global__ __launch_bounds__(512) void k_root(const int* __restrict__ tokens,
    const float* __restrict__ Uiou_t,  // (1536,1536)
    const float* __restrict__ Uf_t,    // (3,512,512)
    const float* __restrict__ Wiou_t, const float* __restrict__ biou_t,
    const float* __restrict__ Wf_t, const float* __restrict__ bf_t) {
  __shared__ float Hr[3 * H];
  int j = threadIdx.x;
  Hr[j] = g_h0[j];            // h of lvl-0 cell (node 0)
  Hr[H + j] = g_h1[j];        // h_ab[0] (node 1)
  Hr[2 * H + j] = g_h1[H + j];// h_ab[1] (node 2)
  __syncthreads();
  float ai = 0, ao = 0, au = 0, f0 = 0, f1 = 0, f2 = 0;
  for (int m = 0; m < H; ++m) {
    float a = Hr[m];
    ai += a * Uiou_t[m * 1536 + j]; ao += a * Uiou_t[m * 1536 + 512 + j];
    au += a * Uiou_t[m * 1536 + 1024 + j]; f0 += a * Uf_t[m * H + j];
  }
  for (int m = H; m < 2 * H; ++m) {
    float a = Hr[m];
    ai += a * Uiou_t[m * 1536 + j]; ao += a * Uiou_t[m * 1536 + 512 + j];
    au += a * Uiou_t[m * 1536 + 1024 + j]; f1 += a * Uf_t[H * H + (m - H) * H + j];
  }
  for (int m = 2 * H; m < 3 * H; ++m) {
    float a = Hr[m];
    ai += a * Uiou_t[m * 1536 + j]; ao += a * Uiou_t[m * 1536 + 512 + j];
    au += a * Uiou_t[m * 1536 + 1024 + j]; f2 += a * Uf_t[2 * H * H + (m - 2 * H) * H + j];
  }
  int tok = tokens[0];
  float fpre = Wf_t[tok * H + j] + bf_t[j];
  float ig = ai + Wiou_t[tok * 3 * H + j] + biou_t[j];
  float og = ao + Wiou_t[tok * 3 * H + H + j] + biou_t[H + j];
  float ug = au + Wiou_t[tok * 3 * H + 2 * H + j] + biou_t[2 * H + j];
  float cc = sigm(ig) * ftanh(ug)
           + sigm(fpre + f0) * g_c0[j]
           + sigm(fpre + f1) * g_c1[j]
           + sigm(fpre + f2) * g_c1[H + j];
  float hh = sigm(og) * ftanh(cc);
  g_root[j] = hh;
  g_root[H + j] = cc;
}

// ---------------- heads ----------------------------------------------------
__global__ __launch_bounds__(512) void k_head1(const float* __restrict__ ffnW,
                                               const float* __restrict__ ffnb) {
  __shared__ float hr[H];
  int j = threadIdx.x;
  hr[j] = g_root[j];
  __syncthreads();
  float acc = ffnb[j];
  for (int m = 0; m < H; ++m) acc += hr[m] * ffnW[m * H + j];
  g_hf[j] = fmaxf(acc, 0.0f);
}

__global__ __launch_bounds__(64) void k_head2(const float* __restrict__ Wx,
                                              const float* __restrict__ lb) {
  int g = blockIdx.x * 64 + threadIdx.x;
  float acc = lb[g];
  for (int m = 0; m < H; ++m) acc += g_hf[m] * Wx[m * 4 * H + g];
  g_gates[g] = acc;  // h_g starts at 0 so Wh term vanishes
}

__global__ __launch_bounds__(512) void k_head3(const float* __restrict__ vm,
    const float* __restrict__ hlW, const float* __restrict__ hlb,
    const float* __restrict__ intW, const float* __restrict__ intb,
    const float* __restrict__ actW, const float* __restrict__ actb,
    float* __restrict__ out) {
  __shared__ float feat[2 * H];
  int j = threadIdx.x;
  float ci = sigm(g_gates[j]) * ftanh(g_gates[2 * H + j]);   // sig(gi)*tanh(gg)
  float hg = sigm(g_gates[3 * H + j]) * ftanh(ci);           // sig(go)*tanh(c)
  feat[j] = g_hf[j];
  feat[H + j] = hg;
  __syncthreads();
  if (j < 43) {
    float acc;
    if (j < 2) {
      acc = hlb[j];
      for (int m = 0; m < 2 * H; ++m) acc += feat[m] * hlW[m * 2 + j];
    } else if (j < 7) {
      int a = j - 2;
      acc = intb[a];
      for (int m = 0; m < 2 * H; ++m) acc += feat[m] * intW[m * 5 + a];
    } else {
      int a = j - 7;
      float v = vm[a];
      float s = 0;
      for (int m = 0; m < 2 * H; ++m) s += feat[m] * actW[m * 36 + a];
      acc = __logf(v) + s * v + actb[a] * v;
    }
    out[j] = acc;
  }
}

extern "C" void kernel_launch(void* const* d_in, const int* in_sizes, int n_in,
                              void* d_out, int out_size, void* d_ws, size_t ws_size,
                              hipStream_t stream) {
  (void)in_sizes; (void)n_in; (void)d_ws; (void)ws_size; (void)out_size;
  const int* tokens  = (const int*)d_in[0];
  const float* vm    = (const float*)d_in[1];
  const float* Wiou_b = (const float*)d_in[2];
  const float* Uiou_b = (const float*)d_in[3];
  const float* biou_b = (const float*)d_in[4];
  const float* Wf_b   = (const float*)d_in[5];
  const float* Uf_b   = (const float*)d_in[6];
  const float* bf_b   = (const float*)d_in[7];
  const float* Wiou_t = (const float*)d_in[8];
  const float* Uiou_t = (const float*)d_in[9];
  const float* biou_t = (const float*)d_in[10];
  const float* Wf_t   = (const float*)d_in[11];
  const float* Uf_t   = (const float*)d_in[12];
  const float* bf_t   = (const float*)d_in[13];
  const float* ffnW   = (const float*)d_in[14];
  const float* ffnb   = (const float*)d_in[15];
  const float* lstmWx = (const float*)d_in[16];
  // d_in[17] = lstm_Wh unused: h_g initial state is 0
  const float* lstmb  = (const float*)d_in[18];
  const float* hlW    = (const float*)d_in[19];
  const float* hlb    = (const float*)d_in[20];
  const float* intW   = (const float*)d_in[21];
  const float* intb   = (const float*)d_in[22];
  const float* actW   = (const float*)d_in[23];
  const float* actb   = (const float*)d_in[24];

  k_leaf<<<NLEAF * H / 256, 256, 0, stream>>>(tokens, Wiou_b, biou_b);
  for (int lvl = 13; lvl >= 6; --lvl)
    k_cell_big<<<dim3((1u << lvl) / 64, 8), 512, 0, stream>>>(
        lvl, tokens, Uiou_b, Uf_b, Wiou_b, biou_b, Wf_b, bf_b);
  for (int lvl = 5; lvl >= 0; --lvl)
    k_cell_small<<<dim3(((1u << lvl) + 7) / 8, 8), 512, 0, stream>>>(
        lvl, tokens, Uiou_b, Uf_b, Wiou_b, biou_b, Wf_b, bf_b);
  k_root<<<1, 512, 0, stream>>>(tokens, Uiou_t, Uf_t, Wiou_t, biou_t, Wf_t, bf_t);
  k_head1<<<1, 512, 0, stream>>>(ffnW, ffnb);
  k_head2<<<32, 64, 0, stream>>>(lstmWx, lstmb);
  k_head3<<<1, 512, 0, stream>>>(vm, hlW, hlb, intW, intb, actW, actb, (float*)d_out);
}

// Round 2
// 1349.570 us; speedup vs baseline: 3.1002x; 3.1002x over previous
//
#include <hip/hip_runtime.h>
#include <hip/hip_bf16.h>
#include <math.h>

#define H 512
#define V 128
#define NLEAF 16384

typedef __attribute__((ext_vector_type(4))) float f32x4;
typedef __attribute__((ext_vector_type(8))) short s16x8;
typedef unsigned short ushort_t;

// ---- static device scratch: h in bf16, c in f32, transposed bf16 weights ----
__device__ ushort_t g_hb0[NLEAF * H];        // 16 MB  (levels 14,12,...,0)
__device__ ushort_t g_hb1[(NLEAF / 2) * H];  // 8 MB   (levels 13,11,...,1)
__device__ float    g_c0[NLEAF * H];         // 32 MB
__device__ float    g_c1[(NLEAF / 2) * H];   // 16 MB
__device__ ushort_t g_UiouT[3 * H * 2 * H];  // [1536 cols][1024 k] bf16
__device__ ushort_t g_UfT[H * 2 * H];        // [512 cols][1024 k] bf16 (f0|f1 k-halves)
__device__ float    g_root[2 * H];
__device__ float    g_hf[H];
__device__ float    g_gates[4 * H];

__device__ __forceinline__ float sigm(float x) { return 1.0f / (1.0f + __expf(-x)); }
__device__ __forceinline__ float ftanh(float x) {
  return 1.0f - 2.0f / (__expf(2.0f * x) + 1.0f);
}
__device__ __forceinline__ ushort_t f2bf(float x) {
  __hip_bfloat16 b = __float2bfloat16(x);
  return *reinterpret_cast<ushort_t*>(&b);
}
__device__ __forceinline__ float bf2f(ushort_t u) {
  union { unsigned int i; float f; } v; v.i = ((unsigned int)u) << 16; return v.f;
}
__device__ __forceinline__ void gload_lds16(const void* g, void* l) {
  __builtin_amdgcn_global_load_lds(
      (const __attribute__((address_space(1))) unsigned int*)g,
      (__attribute__((address_space(3))) unsigned int*)l, 16, 0, 0);
}

// ---------------- weight transpose+convert: dst[c][r] = bf16(src[r][c]) ----
__global__ __launch_bounds__(256) void k_transp(const float* __restrict__ src,
                                                ushort_t* __restrict__ dst,
                                                int R, int Cc) {
  __shared__ float t[32][33];
  int bc = blockIdx.x * 32, br = blockIdx.y * 32;
  int tx = threadIdx.x & 31, ty = threadIdx.x >> 5;  // 32 x 8
  for (int rr = ty; rr < 32; rr += 8)
    t[rr][tx] = src[(size_t)(br + rr) * Cc + bc + tx];
  __syncthreads();
  for (int rr = ty; rr < 32; rr += 8)
    dst[(size_t)(bc + rr) * R + br + tx] = f2bf(t[tx][rr]);
}

// ---------------- leaf level (lvl 14): hk = ck = 0, pure elementwise -------
__global__ __launch_bounds__(256) void k_leaf(const int* __restrict__ tokens,
                                              const float* __restrict__ Wiou,
                                              const float* __restrict__ biou) {
  int idx = blockIdx.x * 256 + threadIdx.x;
  int i = idx >> 9, j = idx & (H - 1);
  int tok = tokens[(NLEAF - 1) + i];
  const float* Wr = Wiou + (size_t)tok * 3 * H;
  float ig = Wr[j] + biou[j];
  float og = Wr[H + j] + biou[H + j];
  float ug = Wr[2 * H + j] + biou[2 * H + j];
  float c = sigm(ig) * ftanh(ug);
  float h = sigm(og) * ftanh(c);
  g_hb0[idx] = f2bf(h);
  g_c0[idx] = c;
}

// ---------------- big levels (n >= 64): MFMA bf16 fused cell ---------------
// block 256 thr = 4 waves (2 row x 2 col). Tile: 128 nodes x 64 j-cols x 5 gates.
// LDS (48KB): A[2][8 rowtiles][1KB frag], B[2][16 coltiles][1KB frag],
// both in MFMA-fragment order -> global_load_lds linear dest, ds_read_b128
// at lane*16 conflict-free (pre-swizzled-source pattern, m173).
__global__ __launch_bounds__(256, 2) void k_mfma_lvl(int lvl,
    const int* __restrict__ tokens,
    const float* __restrict__ Wiou, const float* __restrict__ biou,
    const float* __restrict__ Wf, const float* __restrict__ bf) {
  const int n = 1 << lvl;
  const int node0 = n - 1;
  const int outp = lvl & 1;
  const ushort_t* __restrict__ hprev = outp ? g_hb0 : g_hb1;
  const float* __restrict__ cprev = outp ? g_c0 : g_c1;
  ushort_t* __restrict__ hout = outp ? g_hb1 : g_hb0;
  float* __restrict__ cout = outp ? g_c1 : g_c0;

  const int i0 = blockIdx.x * 128;
  const int j0 = blockIdx.y * 64;
  const int tid = threadIdx.x;
  const int lane = tid & 63;
  const int w = tid >> 6;        // 0..3
  const int wry = w >> 1;        // row half
  const int cx = w & 1;          // col half

  __shared__ f32x4 smemv[3072];  // 48KB
  char* smem = (char*)smemv;

  // per-thread staging sources: wave w stages chunks w*6 .. w*6+5
  const char* gp[6];
  unsigned lb[6], lstride[6];
  {
    int kb = (lane >> 4) * 16;   // byte offset along k (8 bf16)
    #pragma unroll
    for (int q = 0; q < 6; ++q) {
      int c = w * 6 + q;
      if (c < 8) {               // A chunk, row-tile c
        int row = i0 + c * 16 + (lane & 15);
        gp[q] = (const char*)hprev + (size_t)row * 2048 + kb;
        lb[q] = c * 1024u;
        lstride[q] = 8192u;
      } else {                   // B chunk, col-tile ct
        int ct = c - 8;
        int col = ct * 16 + (lane & 15);    // 0..255: [i|o|u|f] x 64
        int g = col >> 6, jj = j0 + (col & 63);
        const ushort_t* Ub = (g < 3) ? (g_UiouT + (size_t)(g * 512 + jj) * 1024)
                                     : (g_UfT + (size_t)jj * 1024);
        gp[q] = (const char*)Ub + kb;
        lb[q] = 16384u + ct * 1024u;
        lstride[q] = 16384u;
      }
    }
  }

#define STAGE(BUF)                                                   \
  {                                                                  \
    _Pragma("unroll")                                                \
    for (int q = 0; q < 6; ++q) {                                    \
      gload_lds16(gp[q], smem + lb[q] + (unsigned)(BUF) * lstride[q]); \
      gp[q] += 64;                                                   \
    }                                                                \
  }

  f32x4 acc[4][10];   // per row-tile: [i0,i1, o0,o1, u0,u1, f0a,f0b, f1a,f1b]
  #pragma unroll
  for (int a = 0; a < 4; ++a)
    #pragma unroll
    for (int b = 0; b < 10; ++b) acc[a][b] = (f32x4){0.f, 0.f, 0.f, 0.f};

#define COMPUTE(FA)                                                          \
  {                                                                          \
    const char* ab = smem + buf * 8192 + wry * 4096 + lane * 16;             \
    s16x8 a0 = *(const s16x8*)(ab);                                          \
    s16x8 a1 = *(const s16x8*)(ab + 1024);                                   \
    s16x8 a2 = *(const s16x8*)(ab + 2048);                                   \
    s16x8 a3 = *(const s16x8*)(ab + 3072);                                   \
    const char* bb = smem + 16384 + buf * 16384 + cx * 2048 + lane * 16;     \
    s16x8 b0 = *(const s16x8*)(bb);                                          \
    s16x8 b1 = *(const s16x8*)(bb + 1024);                                   \
    s16x8 b2 = *(const s16x8*)(bb + 4096);                                   \
    s16x8 b3 = *(const s16x8*)(bb + 5120);                                   \
    s16x8 b4 = *(const s16x8*)(bb + 8192);                                   \
    s16x8 b5 = *(const s16x8*)(bb + 9216);                                   \
    s16x8 b6 = *(const s16x8*)(bb + 12288);                                  \
    s16x8 b7 = *(const s16x8*)(bb + 13312);                                  \
    s16x8 aa[4] = {a0, a1, a2, a3};                                          \
    _Pragma("unroll")                                                        \
    for (int rtl = 0; rtl < 4; ++rtl) {                                      \
      acc[rtl][0] = __builtin_amdgcn_mfma_f32_16x16x32_bf16(aa[rtl], b0, acc[rtl][0], 0, 0, 0); \
      acc[rtl][1] = __builtin_amdgcn_mfma_f32_16x16x32_bf16(aa[rtl], b1, acc[rtl][1], 0, 0, 0); \
      acc[rtl][2] = __builtin_amdgcn_mfma_f32_16x16x32_bf16(aa[rtl], b2, acc[rtl][2], 0, 0, 0); \
      acc[rtl][3] = __builtin_amdgcn_mfma_f32_16x16x32_bf16(aa[rtl], b3, acc[rtl][3], 0, 0, 0); \
      acc[rtl][4] = __builtin_amdgcn_mfma_f32_16x16x32_bf16(aa[rtl], b4, acc[rtl][4], 0, 0, 0); \
      acc[rtl][5] = __builtin_amdgcn_mfma_f32_16x16x32_bf16(aa[rtl], b5, acc[rtl][5], 0, 0, 0); \
      acc[rtl][FA] = __builtin_amdgcn_mfma_f32_16x16x32_bf16(aa[rtl], b6, acc[rtl][FA], 0, 0, 0); \
      acc[rtl][FA + 1] = __builtin_amdgcn_mfma_f32_16x16x32_bf16(aa[rtl], b7, acc[rtl][FA + 1], 0, 0, 0); \
    }                                                                        \
  }

  STAGE(0);
  __syncthreads();
  int buf = 0;
  // k-halves split so f-accumulator indices stay compile-time (rule #20)
  for (int kt = 0; kt < 16; ++kt) {
    STAGE(buf ^ 1);
    COMPUTE(6);
    __syncthreads();
    buf ^= 1;
  }
  for (int kt = 16; kt < 32; ++kt) {
    if (kt < 31) STAGE(buf ^ 1);
    COMPUTE(8);
    __syncthreads();
    buf ^= 1;
  }
#undef COMPUTE
#undef STAGE

  // ---- fused epilogue (f32): C/D layout col=lane&15, row=(lane>>4)*4+reg --
  const int node_c = lane >> 4;
  const int jl = lane & 15;
  #pragma unroll
  for (int t = 0; t < 2; ++t) {
    const int j = j0 + cx * 32 + t * 16 + jl;
    const float bi = biou[j], bo = biou[512 + j], bu = biou[1024 + j], bfv = bf[j];
    #pragma unroll
    for (int rtl = 0; rtl < 4; ++rtl) {
      f32x4 vi = acc[rtl][0 + t], vo = acc[rtl][2 + t], vu = acc[rtl][4 + t],
            v0 = acc[rtl][6 + t], v1 = acc[rtl][8 + t];
      const int ib = i0 + wry * 64 + rtl * 16 + node_c * 4;
      #pragma unroll
      for (int r = 0; r < 4; ++r) {
        int i = ib + r;
        if (i < n) {
          int tok = tokens[node0 + i];
          const float* Wr = Wiou + (size_t)tok * 1536;
          float fpre = Wf[(size_t)tok * 512 + j] + bfv;
          float ig = vi[r] + Wr[j] + bi;
          float og = vo[r] + Wr[512 + j] + bo;
          float ug = vu[r] + Wr[1024 + j] + bu;
          float cc = sigm(ig) * ftanh(ug)
                   + sigm(fpre + v0[r]) * cprev[(size_t)(2 * i) * 512 + j]
                   + sigm(fpre + v1[r]) * cprev[(size_t)(2 * i + 1) * 512 + j];
          float hh = sigm(og) * ftanh(cc);
          hout[(size_t)i * 512 + j] = f2bf(hh);
          cout[(size_t)i * 512 + j] = cc;
        }
      }
    }
  }
}

// ---------------- small levels (n <= 32): latency-oriented -----------------
__global__ __launch_bounds__(512) void k_cell_small(int lvl,
    const int* __restrict__ tokens,
    const float* __restrict__ Uiou, const float* __restrict__ Uf,
    const float* __restrict__ Wiou, const float* __restrict__ biou,
    const float* __restrict__ Wf, const float* __restrict__ bf) {
  const int n = 1 << lvl;
  const int node0 = n - 1;
  const int outp = lvl & 1;
  const ushort_t* __restrict__ hprev = outp ? g_hb0 : g_hb1;
  const float* __restrict__ cprev = outp ? g_c0 : g_c1;
  ushort_t* __restrict__ hout = outp ? g_hb1 : g_hb0;
  float* __restrict__ cout = outp ? g_c1 : g_c0;

  const int tc = threadIdx.x & 63;
  const int nt = threadIdx.x >> 6;
  const int i = blockIdx.x * 8 + nt;
  const int j = (blockIdx.y << 6) + tc;
  if (i >= n) return;

  const ushort_t* hp = hprev + (size_t)i * (2 * H);
  float ai = 0, ao = 0, au = 0, af0 = 0, af1 = 0;
  for (int m = 0; m < H; ++m) {
    float a = bf2f(hp[m]);
    ai += a * Uiou[m * 1536 + j];
    ao += a * Uiou[m * 1536 + 512 + j];
    au += a * Uiou[m * 1536 + 1024 + j];
    af0 += a * Uf[m * H + j];
  }
  for (int m = H; m < 2 * H; ++m) {
    float a = bf2f(hp[m]);
    ai += a * Uiou[m * 1536 + j];
    ao += a * Uiou[m * 1536 + 512 + j];
    au += a * Uiou[m * 1536 + 1024 + j];
    af1 += a * Uf[H * H + (m - H) * H + j];
  }

  int tok = tokens[node0 + i];
  const float* Wr = Wiou + (size_t)tok * 3 * H;
  float fpre = Wf[(size_t)tok * H + j] + bf[j];
  float ig = ai + Wr[j] + biou[j];
  float og = ao + Wr[H + j] + biou[H + j];
  float ug = au + Wr[2 * H + j] + biou[2 * H + j];
  float f0 = sigm(fpre + af0);
  float f1 = sigm(fpre + af1);
  float cc = sigm(ig) * ftanh(ug)
           + f0 * cprev[(size_t)(2 * i) * H + j]
           + f1 * cprev[(size_t)(2 * i + 1) * H + j];
  float hh = sigm(og) * ftanh(cc);
  hout[(size_t)i * H + j] = f2bf(hh);
  cout[(size_t)i * H + j] = cc;
}

// ---------------- root ternary cell ---------------------------------------
__global__ __launch_bounds__(512) void k_root(const int* __restrict__ tokens,
    const float* __restrict__ Uiou_t, const float* __restrict__ Uf_t,
    const float* __restrict__ Wiou_t, const float* __restrict__ biou_t,
    const float* __restrict__ Wf_t, const float* __restrict__ bf_t) {
  __shared__ float Hr[3 * H];
  int j = threadIdx.x;
  Hr[j] = bf2f(g_hb0[j]);           // h of lvl-0 (node 0)
  Hr[H + j] = bf2f(g_hb1[j]);       // h_ab[0] (node 1)
  Hr[2 * H + j] = bf2f(g_hb1[H + j]); // h_ab[1] (node 2)
  __syncthreads();
  float ai = 0, ao = 0, au = 0, f0 = 0, f1 = 0, f2 = 0;
  for (int m = 0; m < H; ++m) {
    float a = Hr[m];
    ai += a * Uiou_t[m * 1536 + j]; ao += a * Uiou_t[m * 1536 + 512 + j];
    au += a * Uiou_t[m * 1536 + 1024 + j]; f0 += a * Uf_t[m * H + j];
  }
  for (int m = H; m < 2 * H; ++m) {
    float a = Hr[m];
    ai += a * Uiou_t[m * 1536 + j]; ao += a * Uiou_t[m * 1536 + 512 + j];
    au += a * Uiou_t[m * 1536 + 1024 + j]; f1 += a * Uf_t[H * H + (m - H) * H + j];
  }
  for (int m = 2 * H; m < 3 * H; ++m) {
    float a = Hr[m];
    ai += a * Uiou_t[m * 1536 + j]; ao += a * Uiou_t[m * 1536 + 512 + j];
    au += a * Uiou_t[m * 1536 + 1024 + j]; f2 += a * Uf_t[2 * H * H + (m - 2 * H) * H + j];
  }
  int tok = tokens[0];
  float fpre = Wf_t[(size_t)tok * H + j] + bf_t[j];
  float ig = ai + Wiou_t[(size_t)tok * 3 * H + j] + biou_t[j];
  float og = ao + Wiou_t[(size_t)tok * 3 * H + H + j] + biou_t[H + j];
  float ug = au + Wiou_t[(size_t)tok * 3 * H + 2 * H + j] + biou_t[2 * H + j];
  float cc = sigm(ig) * ftanh(ug)
           + sigm(fpre + f0) * g_c0[j]
           + sigm(fpre + f1) * g_c1[j]
           + sigm(fpre + f2) * g_c1[H + j];
  float hh = sigm(og) * ftanh(cc);
  g_root[j] = hh;
  g_root[H + j] = cc;
}

// ---------------- heads ----------------------------------------------------
__global__ __launch_bounds__(512) void k_head1(const float* __restrict__ ffnW,
                                               const float* __restrict__ ffnb) {
  __shared__ float hr[H];
  int j = threadIdx.x;
  hr[j] = g_root[j];
  __syncthreads();
  float acc = ffnb[j];
  for (int m = 0; m < H; ++m) acc += hr[m] * ffnW[m * H + j];
  g_hf[j] = fmaxf(acc, 0.0f);
}

__global__ __launch_bounds__(64) void k_head2(const float* __restrict__ Wx,
                                              const float* __restrict__ lb) {
  int g = blockIdx.x * 64 + threadIdx.x;
  float acc = lb[g];
  for (int m = 0; m < H; ++m) acc += g_hf[m] * Wx[m * 4 * H + g];
  g_gates[g] = acc;  // h_g starts at 0 so Wh term vanishes
}

__global__ __launch_bounds__(512) void k_head3(const float* __restrict__ vm,
    const float* __restrict__ hlW, const float* __restrict__ hlb,
    const float* __restrict__ intW, const float* __restrict__ intb,
    const float* __restrict__ actW, const float* __restrict__ actb,
    float* __restrict__ out) {
  __shared__ float feat[2 * H];
  int j = threadIdx.x;
  float ci = sigm(g_gates[j]) * ftanh(g_gates[2 * H + j]);
  float hg = sigm(g_gates[3 * H + j]) * ftanh(ci);
  feat[j] = g_hf[j];
  feat[H + j] = hg;
  __syncthreads();
  if (j < 43) {
    float acc;
    if (j < 2) {
      acc = hlb[j];
      for (int m = 0; m < 2 * H; ++m) acc += feat[m] * hlW[m * 2 + j];
    } else if (j < 7) {
      int a = j - 2;
      acc = intb[a];
      for (int m = 0; m < 2 * H; ++m) acc += feat[m] * intW[m * 5 + a];
    } else {
      int a = j - 7;
      float v = vm[a];
      float s = 0;
      for (int m = 0; m < 2 * H; ++m) s += feat[m] * actW[m * 36 + a];
      acc = __logf(v) + s * v + actb[a] * v;
    }
    out[j] = acc;
  }
}

extern "C" void kernel_launch(void* const* d_in, const int* in_sizes, int n_in,
                              void* d_out, int out_size, void* d_ws, size_t ws_size,
                              hipStream_t stream) {
  (void)in_sizes; (void)n_in; (void)d_ws; (void)ws_size; (void)out_size;
  const int* tokens   = (const int*)d_in[0];
  const float* vm     = (const float*)d_in[1];
  const float* Wiou_b = (const float*)d_in[2];
  const float* Uiou_b = (const float*)d_in[3];
  const float* biou_b = (const float*)d_in[4];
  const float* Wf_b   = (const float*)d_in[5];
  const float* Uf_b   = (const float*)d_in[6];
  const float* bf_b   = (const float*)d_in[7];
  const float* Wiou_t = (const float*)d_in[8];
  const float* Uiou_t = (const float*)d_in[9];
  const float* biou_t = (const float*)d_in[10];
  const float* Wf_t   = (const float*)d_in[11];
  const float* Uf_t   = (const float*)d_in[12];
  const float* bf_t   = (const float*)d_in[13];
  const float* ffnW   = (const float*)d_in[14];
  const float* ffnb   = (const float*)d_in[15];
  const float* lstmWx = (const float*)d_in[16];
  const float* lstmb  = (const float*)d_in[18];
  const float* hlW    = (const float*)d_in[19];
  const float* hlb    = (const float*)d_in[20];
  const float* intW   = (const float*)d_in[21];
  const float* intb   = (const float*)d_in[22];
  const float* actW   = (const float*)d_in[23];
  const float* actb   = (const float*)d_in[24];

  ushort_t* UiouT; hipGetSymbolAddress((void**)&UiouT, HIP_SYMBOL(g_UiouT));
  ushort_t* UfT;   hipGetSymbolAddress((void**)&UfT, HIP_SYMBOL(g_UfT));

  // weight transpose+bf16 convert (runs every call; deterministic)
  k_transp<<<dim3(48, 32), 256, 0, stream>>>(Uiou_b, UiouT, 1024, 1536);
  k_transp<<<dim3(16, 32), 256, 0, stream>>>(Uf_b, UfT, 1024, 512);

  k_leaf<<<NLEAF * H / 256, 256, 0, stream>>>(tokens, Wiou_b, biou_b);
  for (int lvl = 13; lvl >= 6; --lvl) {
    int gx = (1 << lvl) / 128; if (gx < 1) gx = 1;
    k_mfma_lvl<<<dim3(gx, 8), 256, 0, stream>>>(lvl, tokens, Wiou_b, biou_b,
                                                Wf_b, bf_b);
  }
  for (int lvl = 5; lvl >= 0; --lvl)
    k_cell_small<<<dim3(((1u << lvl) + 7) / 8, 8), 512, 0, stream>>>(
        lvl, tokens, Uiou_b, Uf_b, Wiou_b, biou_b, Wf_b, bf_b);
  k_root<<<1, 512, 0, stream>>>(tokens, Uiou_t, Uf_t, Wiou_t, biou_t, Wf_t, bf_t);
  k_head1<<<1, 512, 0, stream>>>(ffnW, ffnb);
  k_head2<<<32, 64, 0, stream>>>(lstmWx, lstmb);
  k_head3<<<1, 512, 0, stream>>>(vm, hlW, hlb, intW, intb, actW, actb, (float*)d_out);
}

// Round 3
// 730.130 us; speedup vs baseline: 5.7303x; 1.8484x over previous
//
#include <hip/hip_runtime.h>
#include <hip/hip_bf16.h>
#include <math.h>

#define H 512
#define V 128
#define NLEAF 16384

typedef __attribute__((ext_vector_type(4))) float f32x4;
typedef __attribute__((ext_vector_type(8))) short s16x8;
typedef unsigned short ushort_t;

// ---- static device scratch ----
__device__ ushort_t g_hb0[NLEAF * H];        // h bf16 (levels 14,12,...,0)
__device__ ushort_t g_hb1[(NLEAF / 2) * H];  // h bf16 (levels 13,11,...,1)
__device__ float    g_c0[NLEAF * H];         // c f32
__device__ float    g_c1[(NLEAF / 2) * H];
__device__ ushort_t g_UiouT[3 * H * 2 * H];  // [1536 cols][1024 k] bf16 (binary)
__device__ ushort_t g_UfT[H * 2 * H];        // [512 cols][1024 k] bf16 (f0|f1 halves)
__device__ ushort_t g_UiouTt[3 * H * 3 * H]; // [1536 cols][1536 k] bf16 (root)
__device__ ushort_t g_UfTt[H * 3 * H];       // [512 cols][1536 k] bf16 (f0|f1|f2 thirds)
__device__ float    g_rpart[3 * 3072];       // root k-chunk partials
__device__ float    g_spart[32 * 2 * 2560];  // small-level partials (n<=32)
__device__ float    g_root[2 * H];
__device__ float    g_hf[H];
__device__ float    g_gates[4 * H];

__device__ __forceinline__ float sigm(float x) { return 1.0f / (1.0f + __expf(-x)); }
__device__ __forceinline__ float ftanh(float x) {
  return 1.0f - 2.0f / (__expf(2.0f * x) + 1.0f);
}
__device__ __forceinline__ ushort_t f2bf(float x) {
  __hip_bfloat16 b = __float2bfloat16(x);
  return *reinterpret_cast<ushort_t*>(&b);
}
__device__ __forceinline__ float bf2f(ushort_t u) {
  union { unsigned int i; float f; } v; v.i = ((unsigned int)u) << 16; return v.f;
}
__device__ __forceinline__ void gload_lds16(const void* g, void* l) {
  __builtin_amdgcn_global_load_lds(
      (const __attribute__((address_space(1))) unsigned int*)g,
      (__attribute__((address_space(3))) unsigned int*)l, 16, 0, 0);
}

// ---------------- weight transpose+convert: dst[c][r] = bf16(src[r][c]) ----
__global__ __launch_bounds__(256) void k_transp(const float* __restrict__ src,
                                                ushort_t* __restrict__ dst,
                                                int R, int Cc) {
  __shared__ float t[32][33];
  int bc = blockIdx.x * 32, br = blockIdx.y * 32;
  int tx = threadIdx.x & 31, ty = threadIdx.x >> 5;  // 32 x 8
  for (int rr = ty; rr < 32; rr += 8)
    t[rr][tx] = src[(size_t)(br + rr) * Cc + bc + tx];
  __syncthreads();
  for (int rr = ty; rr < 32; rr += 8)
    dst[(size_t)(bc + rr) * R + br + tx] = f2bf(t[tx][rr]);
}

// ---------------- leaf level (lvl 14): hk = ck = 0, pure elementwise -------
__global__ __launch_bounds__(256) void k_leaf(const int* __restrict__ tokens,
                                              const float* __restrict__ Wiou,
                                              const float* __restrict__ biou) {
  int idx = blockIdx.x * 256 + threadIdx.x;
  int i = idx >> 9, j = idx & (H - 1);
  int tok = tokens[(NLEAF - 1) + i];
  const float* Wr = Wiou + (size_t)tok * 3 * H;
  float ig = Wr[j] + biou[j];
  float og = Wr[H + j] + biou[H + j];
  float ug = Wr[2 * H + j] + biou[2 * H + j];
  float c = sigm(ig) * ftanh(ug);
  float h = sigm(og) * ftanh(c);
  g_hb0[idx] = f2bf(h);
  g_c0[idx] = c;
}

// ---------------- big levels (n >= 64): MFMA bf16 fused cell ---------------
__global__ __launch_bounds__(256, 2) void k_mfma_lvl(int lvl,
    const int* __restrict__ tokens,
    const float* __restrict__ Wiou, const float* __restrict__ biou,
    const float* __restrict__ Wf, const float* __restrict__ bf) {
  const int n = 1 << lvl;
  const int node0 = n - 1;
  const int outp = lvl & 1;
  const ushort_t* __restrict__ hprev = outp ? g_hb0 : g_hb1;
  const float* __restrict__ cprev = outp ? g_c0 : g_c1;
  ushort_t* __restrict__ hout = outp ? g_hb1 : g_hb0;
  float* __restrict__ cout = outp ? g_c1 : g_c0;

  const int i0 = blockIdx.x * 128;
  const int j0 = blockIdx.y * 64;
  const int tid = threadIdx.x;
  const int lane = tid & 63;
  const int w = tid >> 6;        // 0..3
  const int wry = w >> 1;        // row half
  const int cx = w & 1;          // col half

  __shared__ f32x4 smemv[3072];  // 48KB
  char* smem = (char*)smemv;

  const char* gp[6];
  unsigned lb[6], lstride[6];
  {
    int kb = (lane >> 4) * 16;
    #pragma unroll
    for (int q = 0; q < 6; ++q) {
      int c = w * 6 + q;
      if (c < 8) {               // A chunk, row-tile c
        int row = i0 + c * 16 + (lane & 15);
        gp[q] = (const char*)hprev + (size_t)row * 2048 + kb;
        lb[q] = c * 1024u;
        lstride[q] = 8192u;
      } else {                   // B chunk, col-tile ct
        int ct = c - 8;
        int col = ct * 16 + (lane & 15);
        int g = col >> 6, jj = j0 + (col & 63);
        const ushort_t* Ub = (g < 3) ? (g_UiouT + (size_t)(g * 512 + jj) * 1024)
                                     : (g_UfT + (size_t)jj * 1024);
        gp[q] = (const char*)Ub + kb;
        lb[q] = 16384u + ct * 1024u;
        lstride[q] = 16384u;
      }
    }
  }

#define STAGE(BUF)                                                   \
  {                                                                  \
    _Pragma("unroll")                                                \
    for (int q = 0; q < 6; ++q) {                                    \
      gload_lds16(gp[q], smem + lb[q] + (unsigned)(BUF) * lstride[q]); \
      gp[q] += 64;                                                   \
    }                                                                \
  }

  f32x4 acc[4][10];
  #pragma unroll
  for (int a = 0; a < 4; ++a)
    #pragma unroll
    for (int b = 0; b < 10; ++b) acc[a][b] = (f32x4){0.f, 0.f, 0.f, 0.f};

#define COMPUTE(FA)                                                          \
  {                                                                          \
    const char* ab = smem + buf * 8192 + wry * 4096 + lane * 16;             \
    s16x8 a0 = *(const s16x8*)(ab);                                          \
    s16x8 a1 = *(const s16x8*)(ab + 1024);                                   \
    s16x8 a2 = *(const s16x8*)(ab + 2048);                                   \
    s16x8 a3 = *(const s16x8*)(ab + 3072);                                   \
    const char* bb = smem + 16384 + buf * 16384 + cx * 2048 + lane * 16;     \
    s16x8 b0 = *(const s16x8*)(bb);                                          \
    s16x8 b1 = *(const s16x8*)(bb + 1024);                                   \
    s16x8 b2 = *(const s16x8*)(bb + 4096);                                   \
    s16x8 b3 = *(const s16x8*)(bb + 5120);                                   \
    s16x8 b4 = *(const s16x8*)(bb + 8192);                                   \
    s16x8 b5 = *(const s16x8*)(bb + 9216);                                   \
    s16x8 b6 = *(const s16x8*)(bb + 12288);                                  \
    s16x8 b7 = *(const s16x8*)(bb + 13312);                                  \
    s16x8 aa[4] = {a0, a1, a2, a3};                                          \
    _Pragma("unroll")                                                        \
    for (int rtl = 0; rtl < 4; ++rtl) {                                      \
      acc[rtl][0] = __builtin_amdgcn_mfma_f32_16x16x32_bf16(aa[rtl], b0, acc[rtl][0], 0, 0, 0); \
      acc[rtl][1] = __builtin_amdgcn_mfma_f32_16x16x32_bf16(aa[rtl], b1, acc[rtl][1], 0, 0, 0); \
      acc[rtl][2] = __builtin_amdgcn_mfma_f32_16x16x32_bf16(aa[rtl], b2, acc[rtl][2], 0, 0, 0); \
      acc[rtl][3] = __builtin_amdgcn_mfma_f32_16x16x32_bf16(aa[rtl], b3, acc[rtl][3], 0, 0, 0); \
      acc[rtl][4] = __builtin_amdgcn_mfma_f32_16x16x32_bf16(aa[rtl], b4, acc[rtl][4], 0, 0, 0); \
      acc[rtl][5] = __builtin_amdgcn_mfma_f32_16x16x32_bf16(aa[rtl], b5, acc[rtl][5], 0, 0, 0); \
      acc[rtl][FA] = __builtin_amdgcn_mfma_f32_16x16x32_bf16(aa[rtl], b6, acc[rtl][FA], 0, 0, 0); \
      acc[rtl][FA + 1] = __builtin_amdgcn_mfma_f32_16x16x32_bf16(aa[rtl], b7, acc[rtl][FA + 1], 0, 0, 0); \
    }                                                                        \
  }

  STAGE(0);
  __syncthreads();
  int buf = 0;
  for (int kt = 0; kt < 16; ++kt) {
    STAGE(buf ^ 1);
    COMPUTE(6);
    __syncthreads();
    buf ^= 1;
  }
  for (int kt = 16; kt < 32; ++kt) {
    if (kt < 31) STAGE(buf ^ 1);
    COMPUTE(8);
    __syncthreads();
    buf ^= 1;
  }
#undef COMPUTE
#undef STAGE

  const int node_c = lane >> 4;
  const int jl = lane & 15;
  #pragma unroll
  for (int t = 0; t < 2; ++t) {
    const int j = j0 + cx * 32 + t * 16 + jl;
    const float bi = biou[j], bo = biou[512 + j], bu = biou[1024 + j], bfv = bf[j];
    #pragma unroll
    for (int rtl = 0; rtl < 4; ++rtl) {
      f32x4 vi = acc[rtl][0 + t], vo = acc[rtl][2 + t], vu = acc[rtl][4 + t],
            v0 = acc[rtl][6 + t], v1 = acc[rtl][8 + t];
      const int ib = i0 + wry * 64 + rtl * 16 + node_c * 4;
      #pragma unroll
      for (int r = 0; r < 4; ++r) {
        int i = ib + r;
        if (i < n) {
          int tok = tokens[node0 + i];
          const float* Wr = Wiou + (size_t)tok * 1536;
          float fpre = Wf[(size_t)tok * 512 + j] + bfv;
          float ig = vi[r] + Wr[j] + bi;
          float og = vo[r] + Wr[512 + j] + bo;
          float ug = vu[r] + Wr[1024 + j] + bu;
          float cc = sigm(ig) * ftanh(ug)
                   + sigm(fpre + v0[r]) * cprev[(size_t)(2 * i) * 512 + j]
                   + sigm(fpre + v1[r]) * cprev[(size_t)(2 * i + 1) * 512 + j];
          float hh = sigm(og) * ftanh(cc);
          hout[(size_t)i * 512 + j] = f2bf(hh);
          cout[(size_t)i * 512 + j] = cc;
        }
      }
    }
  }
}

// ------------- small levels (n <= 32): 2-phase k-split GEMV ----------------
// phase 1: grid (10 unit-chunks, 2 k-halves, n nodes), 256 thr.
// unit c<1536: iou col c (j=c&511,g=c>>9); c in [1536,2560): f half-dot,
// active only in its matching k-half (f halves align with k-chunking).
__global__ __launch_bounds__(256) void k_sm_p1(int lvl) {
  const int outp = lvl & 1;
  const ushort_t* __restrict__ hprev = outp ? g_hb0 : g_hb1;
  const int i = blockIdx.z;
  const int by = blockIdx.y;
  const int tid = threadIdx.x;
  const int c = blockIdx.x * 256 + tid;      // 0..2559

  __shared__ float hl[512];
  hl[tid] = bf2f(hprev[(size_t)i * 1024 + by * 512 + tid]);
  hl[256 + tid] = bf2f(hprev[(size_t)i * 1024 + by * 512 + 256 + tid]);
  __syncthreads();

  float acc = 0.f;
  const ushort_t* col = nullptr;
  if (c < 1536) {
    col = g_UiouT + (size_t)c * 1024 + by * 512;
  } else {
    int v = c - 1536;
    if ((v >> 9) == by) col = g_UfT + (size_t)(v & 511) * 1024 + by * 512;
  }
  if (col) {
    #pragma unroll 4
    for (int k0 = 0; k0 < 512; k0 += 8) {
      s16x8 wv = *(const s16x8*)(col + k0);
      #pragma unroll
      for (int r = 0; r < 8; ++r) acc += hl[k0 + r] * bf2f((ushort_t)wv[r]);
    }
  }
  g_spart[((size_t)i * 2 + by) * 2560 + c] = acc;
}

// phase 2: grid (n), 512 thr: sum 2 partials per gate + fused cell epilogue
__global__ __launch_bounds__(512) void k_sm_p2(int lvl,
    const int* __restrict__ tokens,
    const float* __restrict__ Wiou, const float* __restrict__ biou,
    const float* __restrict__ Wf, const float* __restrict__ bf) {
  const int n = 1 << lvl;
  const int node0 = n - 1;
  const int outp = lvl & 1;
  const float* __restrict__ cprev = outp ? g_c0 : g_c1;
  ushort_t* __restrict__ hout = outp ? g_hb1 : g_hb0;
  float* __restrict__ cout = outp ? g_c1 : g_c0;

  const int i = blockIdx.x;
  const int j = threadIdx.x;
  const float* sp = g_spart + (size_t)i * 2 * 2560;

  float ai = sp[j] + sp[2560 + j];
  float ao = sp[512 + j] + sp[2560 + 512 + j];
  float au = sp[1024 + j] + sp[2560 + 1024 + j];
  float af0 = sp[1536 + j] + sp[2560 + 1536 + j];
  float af1 = sp[2048 + j] + sp[2560 + 2048 + j];

  int tok = tokens[node0 + i];
  const float* Wr = Wiou + (size_t)tok * 1536;
  float fpre = Wf[(size_t)tok * 512 + j] + bf[j];
  float ig = ai + Wr[j] + biou[j];
  float og = ao + Wr[512 + j] + biou[512 + j];
  float ug = au + Wr[1024 + j] + biou[1024 + j];
  float cc = sigm(ig) * ftanh(ug)
           + sigm(fpre + af0) * cprev[(size_t)(2 * i) * 512 + j]
           + sigm(fpre + af1) * cprev[(size_t)(2 * i + 1) * 512 + j];
  float hh = sigm(og) * ftanh(cc);
  hout[(size_t)i * 512 + j] = f2bf(hh);
  cout[(size_t)i * 512 + j] = cc;
}

// ---------------- root ternary cell: 2-phase k-split -----------------------
// phase 1: grid (12 unit-chunks, 3 k-thirds), 256 thr. units: 1536 iou +
// 1536 f third-dots.
__global__ __launch_bounds__(256) void k_root_p1() {
  const int by = blockIdx.y;
  const int tid = threadIdx.x;
  const int c = blockIdx.x * 256 + tid;      // 0..3071

  __shared__ float hl[512];
  {
    int m0 = by * 512;
    #pragma unroll
    for (int q = 0; q < 2; ++q) {
      int t = tid + q * 256, m = m0 + t;
      hl[t] = (m < 512) ? bf2f(g_hb0[m]) : bf2f(g_hb1[m - 512]);
    }
  }
  __syncthreads();

  float acc = 0.f;
  const ushort_t* col = nullptr;
  if (c < 1536) {
    col = g_UiouTt + (size_t)c * 1536 + by * 512;
  } else {
    int v = c - 1536;
    if ((v >> 9) == by) col = g_UfTt + (size_t)(v & 511) * 1536 + by * 512;
  }
  if (col) {
    #pragma unroll 4
    for (int k0 = 0; k0 < 512; k0 += 8) {
      s16x8 wv = *(const s16x8*)(col + k0);
      #pragma unroll
      for (int r = 0; r < 8; ++r) acc += hl[k0 + r] * bf2f((ushort_t)wv[r]);
    }
  }
  g_rpart[(size_t)by * 3072 + c] = acc;
}

__global__ __launch_bounds__(512) void k_root_p2(const int* __restrict__ tokens,
    const float* __restrict__ Wiou_t, const float* __restrict__ biou_t,
    const float* __restrict__ Wf_t, const float* __restrict__ bf_t) {
  const int j = threadIdx.x;
  float ai = g_rpart[j] + g_rpart[3072 + j] + g_rpart[6144 + j];
  float ao = g_rpart[512 + j] + g_rpart[3072 + 512 + j] + g_rpart[6144 + 512 + j];
  float au = g_rpart[1024 + j] + g_rpart[3072 + 1024 + j] + g_rpart[6144 + 1024 + j];
  float f0 = g_rpart[1536 + j] + g_rpart[3072 + 1536 + j] + g_rpart[6144 + 1536 + j];
  float f1 = g_rpart[2048 + j] + g_rpart[3072 + 2048 + j] + g_rpart[6144 + 2048 + j];
  float f2 = g_rpart[2560 + j] + g_rpart[3072 + 2560 + j] + g_rpart[6144 + 2560 + j];

  int tok = tokens[0];
  float fpre = Wf_t[(size_t)tok * H + j] + bf_t[j];
  float ig = ai + Wiou_t[(size_t)tok * 3 * H + j] + biou_t[j];
  float og = ao + Wiou_t[(size_t)tok * 3 * H + H + j] + biou_t[H + j];
  float ug = au + Wiou_t[(size_t)tok * 3 * H + 2 * H + j] + biou_t[2 * H + j];
  float cc = sigm(ig) * ftanh(ug)
           + sigm(fpre + f0) * g_c0[j]
           + sigm(fpre + f1) * g_c1[j]
           + sigm(fpre + f2) * g_c1[H + j];
  float hh = sigm(og) * ftanh(cc);
  g_root[j] = hh;
  g_root[H + j] = cc;
}

// ---------------- heads ----------------------------------------------------
__global__ __launch_bounds__(512) void k_head1(const float* __restrict__ ffnW,
                                               const float* __restrict__ ffnb) {
  __shared__ float hr[H];
  int j = threadIdx.x;
  hr[j] = g_root[j];
  __syncthreads();
  float acc = ffnb[j];
  for (int m = 0; m < H; ++m) acc += hr[m] * ffnW[m * H + j];
  g_hf[j] = fmaxf(acc, 0.0f);
}

__global__ __launch_bounds__(64) void k_head2(const float* __restrict__ Wx,
                                              const float* __restrict__ lb) {
  int g = blockIdx.x * 64 + threadIdx.x;
  float acc = lb[g];
  for (int m = 0; m < H; ++m) acc += g_hf[m] * Wx[m * 4 * H + g];
  g_gates[g] = acc;  // h_g starts at 0 so Wh term vanishes
}

__global__ __launch_bounds__(512) void k_head3(const float* __restrict__ vm,
    const float* __restrict__ hlW, const float* __restrict__ hlb,
    const float* __restrict__ intW, const float* __restrict__ intb,
    const float* __restrict__ actW, const float* __restrict__ actb,
    float* __restrict__ out) {
  __shared__ float feat[2 * H];
  int j = threadIdx.x;
  float ci = sigm(g_gates[j]) * ftanh(g_gates[2 * H + j]);
  float hg = sigm(g_gates[3 * H + j]) * ftanh(ci);
  feat[j] = g_hf[j];
  feat[H + j] = hg;
  __syncthreads();
  if (j < 43) {
    float acc;
    if (j < 2) {
      acc = hlb[j];
      for (int m = 0; m < 2 * H; ++m) acc += feat[m] * hlW[m * 2 + j];
    } else if (j < 7) {
      int a = j - 2;
      acc = intb[a];
      for (int m = 0; m < 2 * H; ++m) acc += feat[m] * intW[m * 5 + a];
    } else {
      int a = j - 7;
      float v = vm[a];
      float s = 0;
      for (int m = 0; m < 2 * H; ++m) s += feat[m] * actW[m * 36 + a];
      acc = __logf(v) + s * v + actb[a] * v;
    }
    out[j] = acc;
  }
}

extern "C" void kernel_launch(void* const* d_in, const int* in_sizes, int n_in,
                              void* d_out, int out_size, void* d_ws, size_t ws_size,
                              hipStream_t stream) {
  (void)in_sizes; (void)n_in; (void)d_ws; (void)ws_size; (void)out_size;
  const int* tokens   = (const int*)d_in[0];
  const float* vm     = (const float*)d_in[1];
  const float* Wiou_b = (const float*)d_in[2];
  const float* Uiou_b = (const float*)d_in[3];
  const float* biou_b = (const float*)d_in[4];
  const float* Wf_b   = (const float*)d_in[5];
  const float* Uf_b   = (const float*)d_in[6];
  const float* bf_b   = (const float*)d_in[7];
  const float* Wiou_t = (const float*)d_in[8];
  const float* Uiou_t = (const float*)d_in[9];
  const float* biou_t = (const float*)d_in[10];
  const float* Wf_t   = (const float*)d_in[11];
  const float* Uf_t   = (const float*)d_in[12];
  const float* bf_t   = (const float*)d_in[13];
  const float* ffnW   = (const float*)d_in[14];
  const float* ffnb   = (const float*)d_in[15];
  const float* lstmWx = (const float*)d_in[16];
  const float* lstmb  = (const float*)d_in[18];
  const float* hlW    = (const float*)d_in[19];
  const float* hlb    = (const float*)d_in[20];
  const float* intW   = (const float*)d_in[21];
  const float* intb   = (const float*)d_in[22];
  const float* actW   = (const float*)d_in[23];
  const float* actb   = (const float*)d_in[24];

  ushort_t* UiouT;  hipGetSymbolAddress((void**)&UiouT, HIP_SYMBOL(g_UiouT));
  ushort_t* UfT;    hipGetSymbolAddress((void**)&UfT, HIP_SYMBOL(g_UfT));
  ushort_t* UiouTt; hipGetSymbolAddress((void**)&UiouTt, HIP_SYMBOL(g_UiouTt));
  ushort_t* UfTt;   hipGetSymbolAddress((void**)&UfTt, HIP_SYMBOL(g_UfTt));

  // weight transpose+bf16 convert (every call; deterministic)
  k_transp<<<dim3(48, 32), 256, 0, stream>>>(Uiou_b, UiouT, 1024, 1536);
  k_transp<<<dim3(16, 32), 256, 0, stream>>>(Uf_b, UfT, 1024, 512);
  k_transp<<<dim3(48, 48), 256, 0, stream>>>(Uiou_t, UiouTt, 1536, 1536);
  k_transp<<<dim3(16, 48), 256, 0, stream>>>(Uf_t, UfTt, 1536, 512);

  k_leaf<<<NLEAF * H / 256, 256, 0, stream>>>(tokens, Wiou_b, biou_b);
  for (int lvl = 13; lvl >= 6; --lvl) {
    int gx = (1 << lvl) / 128; if (gx < 1) gx = 1;
    k_mfma_lvl<<<dim3(gx, 8), 256, 0, stream>>>(lvl, tokens, Wiou_b, biou_b,
                                                Wf_b, bf_b);
  }
  for (int lvl = 5; lvl >= 0; --lvl) {
    int n = 1 << lvl;
    k_sm_p1<<<dim3(10, 2, n), 256, 0, stream>>>(lvl);
    k_sm_p2<<<n, 512, 0, stream>>>(lvl, tokens, Wiou_b, biou_b, Wf_b, bf_b);
  }
  k_root_p1<<<dim3(12, 3), 256, 0, stream>>>();
  k_root_p2<<<1, 512, 0, stream>>>(tokens, Wiou_t, biou_t, Wf_t, bf_t);
  k_head1<<<1, 512, 0, stream>>>(ffnW, ffnb);
  k_head2<<<32, 64, 0, stream>>>(lstmWx, lstmb);
  k_head3<<<1, 512, 0, stream>>>(vm, hlW, hlb, intW, intb, actW, actb, (float*)d_out);
}

// Round 4
// 671.888 us; speedup vs baseline: 6.2270x; 1.0867x over previous
//
#include <hip/hip_runtime.h>
#include <hip/hip_bf16.h>
#include <math.h>

#define H 512
#define V 128
#define NLEAF 16384

typedef __attribute__((ext_vector_type(4))) float f32x4;
typedef __attribute__((ext_vector_type(8))) short s16x8;
typedef unsigned short ushort_t;

// ---- static device scratch ----
__device__ ushort_t g_hb0[NLEAF * H];        // h bf16 (levels 14,12,...,0)
__device__ ushort_t g_hb1[(NLEAF / 2) * H];  // h bf16 (levels 13,11,...,1)
__device__ float    g_c0[NLEAF * H];         // c f32
__device__ float    g_c1[(NLEAF / 2) * H];
__device__ ushort_t g_UiouT[3 * H * 2 * H];  // [1536 cols][1024 k] bf16 (binary)
__device__ ushort_t g_UfT[H * 2 * H];        // [512 cols][1024 k] bf16 (f0|f1 halves)
__device__ ushort_t g_UiouTt[3 * H * 3 * H]; // [1536 cols][1536 k] bf16 (root)
__device__ ushort_t g_UfTt[H * 3 * H];       // [512 cols][1536 k] bf16 (f0|f1|f2 thirds)
__device__ float    g_rpart[3 * 3072];       // root k-chunk partials
__device__ float    g_spart[32 * 2 * 2560];  // small-level partials (n<=32)
__device__ float    g_root[2 * H];
__device__ float    g_hf[H];
__device__ float    g_gates[4 * H];

__device__ __forceinline__ float sigm(float x) { return 1.0f / (1.0f + __expf(-x)); }
__device__ __forceinline__ float ftanh(float x) {
  return 1.0f - 2.0f / (__expf(2.0f * x) + 1.0f);
}
__device__ __forceinline__ ushort_t f2bf(float x) {
  __hip_bfloat16 b = __float2bfloat16(x);
  return *reinterpret_cast<ushort_t*>(&b);
}
__device__ __forceinline__ float bf2f(ushort_t u) {
  union { unsigned int i; float f; } v; v.i = ((unsigned int)u) << 16; return v.f;
}
__device__ __forceinline__ void gload_lds16(const void* g, void* l) {
  __builtin_amdgcn_global_load_lds(
      (const __attribute__((address_space(1))) unsigned int*)g,
      (__attribute__((address_space(3))) unsigned int*)l, 16, 0, 0);
}

// ---------------- weight transpose+convert: dst[c][r] = bf16(src[r][c]) ----
__global__ __launch_bounds__(256) void k_transp(const float* __restrict__ src,
                                                ushort_t* __restrict__ dst,
                                                int R, int Cc) {
  __shared__ float t[32][33];
  int bc = blockIdx.x * 32, br = blockIdx.y * 32;
  int tx = threadIdx.x & 31, ty = threadIdx.x >> 5;  // 32 x 8
  for (int rr = ty; rr < 32; rr += 8)
    t[rr][tx] = src[(size_t)(br + rr) * Cc + bc + tx];
  __syncthreads();
  for (int rr = ty; rr < 32; rr += 8)
    dst[(size_t)(bc + rr) * R + br + tx] = f2bf(t[tx][rr]);
}

// ---------------- leaf level (lvl 14): hk = ck = 0, pure elementwise -------
__global__ __launch_bounds__(256) void k_leaf(const int* __restrict__ tokens,
                                              const float* __restrict__ Wiou,
                                              const float* __restrict__ biou) {
  int idx = blockIdx.x * 256 + threadIdx.x;
  int i = idx >> 9, j = idx & (H - 1);
  int tok = tokens[(NLEAF - 1) + i];
  const float* Wr = Wiou + (size_t)tok * 3 * H;
  float ig = Wr[j] + biou[j];
  float og = Wr[H + j] + biou[H + j];
  float ug = Wr[2 * H + j] + biou[2 * H + j];
  float c = sigm(ig) * ftanh(ug);
  float h = sigm(og) * ftanh(c);
  g_hb0[idx] = f2bf(h);
  g_c0[idx] = c;
}

// ---------------- big levels (n >= 64): MFMA bf16 fused cell ---------------
__global__ __launch_bounds__(256, 2) void k_mfma_lvl(int lvl,
    const int* __restrict__ tokens,
    const float* __restrict__ Wiou, const float* __restrict__ biou,
    const float* __restrict__ Wf, const float* __restrict__ bf) {
  const int n = 1 << lvl;
  const int node0 = n - 1;
  const int outp = lvl & 1;
  const ushort_t* __restrict__ hprev = outp ? g_hb0 : g_hb1;
  const float* __restrict__ cprev = outp ? g_c0 : g_c1;
  ushort_t* __restrict__ hout = outp ? g_hb1 : g_hb0;
  float* __restrict__ cout = outp ? g_c1 : g_c0;

  const int i0 = blockIdx.x * 128;
  const int j0 = blockIdx.y * 64;
  const int tid = threadIdx.x;
  const int lane = tid & 63;
  const int w = tid >> 6;        // 0..3
  const int wry = w >> 1;        // row half
  const int cx = w & 1;          // col half

  __shared__ f32x4 smemv[3072];  // 48KB
  char* smem = (char*)smemv;

  const char* gp[6];
  unsigned lb[6], lstride[6];
  {
    int kb = (lane >> 4) * 16;
    #pragma unroll
    for (int q = 0; q < 6; ++q) {
      int c = w * 6 + q;
      if (c < 8) {               // A chunk, row-tile c
        int row = i0 + c * 16 + (lane & 15);
        gp[q] = (const char*)hprev + (size_t)row * 2048 + kb;
        lb[q] = c * 1024u;
        lstride[q] = 8192u;
      } else {                   // B chunk, col-tile ct
        int ct = c - 8;
        int col = ct * 16 + (lane & 15);
        int g = col >> 6, jj = j0 + (col & 63);
        const ushort_t* Ub = (g < 3) ? (g_UiouT + (size_t)(g * 512 + jj) * 1024)
                                     : (g_UfT + (size_t)jj * 1024);
        gp[q] = (const char*)Ub + kb;
        lb[q] = 16384u + ct * 1024u;
        lstride[q] = 16384u;
      }
    }
  }

#define STAGE(BUF)                                                   \
  {                                                                  \
    _Pragma("unroll")                                                \
    for (int q = 0; q < 6; ++q) {                                    \
      gload_lds16(gp[q], smem + lb[q] + (unsigned)(BUF) * lstride[q]); \
      gp[q] += 64;                                                   \
    }                                                                \
  }

  f32x4 acc[4][10];
  #pragma unroll
  for (int a = 0; a < 4; ++a)
    #pragma unroll
    for (int b = 0; b < 10; ++b) acc[a][b] = (f32x4){0.f, 0.f, 0.f, 0.f};

#define COMPUTE(FA)                                                          \
  {                                                                          \
    const char* ab = smem + buf * 8192 + wry * 4096 + lane * 16;             \
    s16x8 a0 = *(const s16x8*)(ab);                                          \
    s16x8 a1 = *(const s16x8*)(ab + 1024);                                   \
    s16x8 a2 = *(const s16x8*)(ab + 2048);                                   \
    s16x8 a3 = *(const s16x8*)(ab + 3072);                                   \
    const char* bb = smem + 16384 + buf * 16384 + cx * 2048 + lane * 16;     \
    s16x8 b0 = *(const s16x8*)(bb);                                          \
    s16x8 b1 = *(const s16x8*)(bb + 1024);                                   \
    s16x8 b2 = *(const s16x8*)(bb + 4096);                                   \
    s16x8 b3 = *(const s16x8*)(bb + 5120);                                   \
    s16x8 b4 = *(const s16x8*)(bb + 8192);                                   \
    s16x8 b5 = *(const s16x8*)(bb + 9216);                                   \
    s16x8 b6 = *(const s16x8*)(bb + 12288);                                  \
    s16x8 b7 = *(const s16x8*)(bb + 13312);                                  \
    s16x8 aa[4] = {a0, a1, a2, a3};                                          \
    _Pragma("unroll")                                                        \
    for (int rtl = 0; rtl < 4; ++rtl) {                                      \
      acc[rtl][0] = __builtin_amdgcn_mfma_f32_16x16x32_bf16(aa[rtl], b0, acc[rtl][0], 0, 0, 0); \
      acc[rtl][1] = __builtin_amdgcn_mfma_f32_16x16x32_bf16(aa[rtl], b1, acc[rtl][1], 0, 0, 0); \
      acc[rtl][2] = __builtin_amdgcn_mfma_f32_16x16x32_bf16(aa[rtl], b2, acc[rtl][2], 0, 0, 0); \
      acc[rtl][3] = __builtin_amdgcn_mfma_f32_16x16x32_bf16(aa[rtl], b3, acc[rtl][3], 0, 0, 0); \
      acc[rtl][4] = __builtin_amdgcn_mfma_f32_16x16x32_bf16(aa[rtl], b4, acc[rtl][4], 0, 0, 0); \
      acc[rtl][5] = __builtin_amdgcn_mfma_f32_16x16x32_bf16(aa[rtl], b5, acc[rtl][5], 0, 0, 0); \
      acc[rtl][FA] = __builtin_amdgcn_mfma_f32_16x16x32_bf16(aa[rtl], b6, acc[rtl][FA], 0, 0, 0); \
      acc[rtl][FA + 1] = __builtin_amdgcn_mfma_f32_16x16x32_bf16(aa[rtl], b7, acc[rtl][FA + 1], 0, 0, 0); \
    }                                                                        \
  }

  STAGE(0);
  __syncthreads();
  int buf = 0;
  for (int kt = 0; kt < 16; ++kt) {
    STAGE(buf ^ 1);
    COMPUTE(6);
    __syncthreads();
    buf ^= 1;
  }
  for (int kt = 16; kt < 32; ++kt) {
    if (kt < 31) STAGE(buf ^ 1);
    COMPUTE(8);
    __syncthreads();
    buf ^= 1;
  }
#undef COMPUTE
#undef STAGE

  const int node_c = lane >> 4;
  const int jl = lane & 15;
  #pragma unroll
  for (int t = 0; t < 2; ++t) {
    const int j = j0 + cx * 32 + t * 16 + jl;
    const float bi = biou[j], bo = biou[512 + j], bu = biou[1024 + j], bfv = bf[j];
    #pragma unroll
    for (int rtl = 0; rtl < 4; ++rtl) {
      f32x4 vi = acc[rtl][0 + t], vo = acc[rtl][2 + t], vu = acc[rtl][4 + t],
            v0 = acc[rtl][6 + t], v1 = acc[rtl][8 + t];
      const int ib = i0 + wry * 64 + rtl * 16 + node_c * 4;
      #pragma unroll
      for (int r = 0; r < 4; ++r) {
        int i = ib + r;
        if (i < n) {
          int tok = tokens[node0 + i];
          const float* Wr = Wiou + (size_t)tok * 1536;
          float fpre = Wf[(size_t)tok * 512 + j] + bfv;
          float ig = vi[r] + Wr[j] + bi;
          float og = vo[r] + Wr[512 + j] + bo;
          float ug = vu[r] + Wr[1024 + j] + bu;
          float cc = sigm(ig) * ftanh(ug)
                   + sigm(fpre + v0[r]) * cprev[(size_t)(2 * i) * 512 + j]
                   + sigm(fpre + v1[r]) * cprev[(size_t)(2 * i + 1) * 512 + j];
          float hh = sigm(og) * ftanh(cc);
          hout[(size_t)i * 512 + j] = f2bf(hh);
          cout[(size_t)i * 512 + j] = cc;
        }
      }
    }
  }
}

// ------------- small levels (n <= 32): 2-phase k-split GEMV ----------------
__global__ __launch_bounds__(256) void k_sm_p1(int lvl) {
  const int outp = lvl & 1;
  const ushort_t* __restrict__ hprev = outp ? g_hb0 : g_hb1;
  const int i = blockIdx.z;
  const int by = blockIdx.y;
  const int tid = threadIdx.x;
  const int c = blockIdx.x * 256 + tid;      // 0..2559

  __shared__ float hl[512];
  hl[tid] = bf2f(hprev[(size_t)i * 1024 + by * 512 + tid]);
  hl[256 + tid] = bf2f(hprev[(size_t)i * 1024 + by * 512 + 256 + tid]);
  __syncthreads();

  float acc = 0.f;
  const ushort_t* col = nullptr;
  if (c < 1536) {
    col = g_UiouT + (size_t)c * 1024 + by * 512;
  } else {
    int v = c - 1536;
    if ((v >> 9) == by) col = g_UfT + (size_t)(v & 511) * 1024 + by * 512;
  }
  if (col) {
    #pragma unroll 4
    for (int k0 = 0; k0 < 512; k0 += 8) {
      s16x8 wv = *(const s16x8*)(col + k0);
      #pragma unroll
      for (int r = 0; r < 8; ++r) acc += hl[k0 + r] * bf2f((ushort_t)wv[r]);
    }
  }
  g_spart[((size_t)i * 2 + by) * 2560 + c] = acc;
}

__global__ __launch_bounds__(512) void k_sm_p2(int lvl,
    const int* __restrict__ tokens,
    const float* __restrict__ Wiou, const float* __restrict__ biou,
    const float* __restrict__ Wf, const float* __restrict__ bf) {
  const int n = 1 << lvl;
  const int node0 = n - 1;
  const int outp = lvl & 1;
  const float* __restrict__ cprev = outp ? g_c0 : g_c1;
  ushort_t* __restrict__ hout = outp ? g_hb1 : g_hb0;
  float* __restrict__ cout = outp ? g_c1 : g_c0;

  const int i = blockIdx.x;
  const int j = threadIdx.x;
  const float* sp = g_spart + (size_t)i * 2 * 2560;

  float ai = sp[j] + sp[2560 + j];
  float ao = sp[512 + j] + sp[2560 + 512 + j];
  float au = sp[1024 + j] + sp[2560 + 1024 + j];
  float af0 = sp[1536 + j] + sp[2560 + 1536 + j];
  float af1 = sp[2048 + j] + sp[2560 + 2048 + j];

  int tok = tokens[node0 + i];
  const float* Wr = Wiou + (size_t)tok * 1536;
  float fpre = Wf[(size_t)tok * 512 + j] + bf[j];
  float ig = ai + Wr[j] + biou[j];
  float og = ao + Wr[512 + j] + biou[512 + j];
  float ug = au + Wr[1024 + j] + biou[1024 + j];
  float cc = sigm(ig) * ftanh(ug)
           + sigm(fpre + af0) * cprev[(size_t)(2 * i) * 512 + j]
           + sigm(fpre + af1) * cprev[(size_t)(2 * i + 1) * 512 + j];
  float hh = sigm(og) * ftanh(cc);
  hout[(size_t)i * 512 + j] = f2bf(hh);
  cout[(size_t)i * 512 + j] = cc;
}

// ---------------- root ternary cell: 2-phase k-split -----------------------
__global__ __launch_bounds__(256) void k_root_p1() {
  const int by = blockIdx.y;
  const int tid = threadIdx.x;
  const int c = blockIdx.x * 256 + tid;      // 0..3071

  __shared__ float hl[512];
  {
    int m0 = by * 512;
    #pragma unroll
    for (int q = 0; q < 2; ++q) {
      int t = tid + q * 256, m = m0 + t;
      hl[t] = (m < 512) ? bf2f(g_hb0[m]) : bf2f(g_hb1[m - 512]);
    }
  }
  __syncthreads();

  float acc = 0.f;
  const ushort_t* col = nullptr;
  if (c < 1536) {
    col = g_UiouTt + (size_t)c * 1536 + by * 512;
  } else {
    int v = c - 1536;
    if ((v >> 9) == by) col = g_UfTt + (size_t)(v & 511) * 1536 + by * 512;
  }
  if (col) {
    #pragma unroll 4
    for (int k0 = 0; k0 < 512; k0 += 8) {
      s16x8 wv = *(const s16x8*)(col + k0);
      #pragma unroll
      for (int r = 0; r < 8; ++r) acc += hl[k0 + r] * bf2f((ushort_t)wv[r]);
    }
  }
  g_rpart[(size_t)by * 3072 + c] = acc;
}

__global__ __launch_bounds__(512) void k_root_p2(const int* __restrict__ tokens,
    const float* __restrict__ Wiou_t, const float* __restrict__ biou_t,
    const float* __restrict__ Wf_t, const float* __restrict__ bf_t) {
  const int j = threadIdx.x;
  float ai = g_rpart[j] + g_rpart[3072 + j] + g_rpart[6144 + j];
  float ao = g_rpart[512 + j] + g_rpart[3072 + 512 + j] + g_rpart[6144 + 512 + j];
  float au = g_rpart[1024 + j] + g_rpart[3072 + 1024 + j] + g_rpart[6144 + 1024 + j];
  float f0 = g_rpart[1536 + j] + g_rpart[3072 + 1536 + j] + g_rpart[6144 + 1536 + j];
  float f1 = g_rpart[2048 + j] + g_rpart[3072 + 2048 + j] + g_rpart[6144 + 2048 + j];
  float f2 = g_rpart[2560 + j] + g_rpart[3072 + 2560 + j] + g_rpart[6144 + 2560 + j];

  int tok = tokens[0];
  float fpre = Wf_t[(size_t)tok * H + j] + bf_t[j];
  float ig = ai + Wiou_t[(size_t)tok * 3 * H + j] + biou_t[j];
  float og = ao + Wiou_t[(size_t)tok * 3 * H + H + j] + biou_t[H + j];
  float ug = au + Wiou_t[(size_t)tok * 3 * H + 2 * H + j] + biou_t[2 * H + j];
  float cc = sigm(ig) * ftanh(ug)
           + sigm(fpre + f0) * g_c0[j]
           + sigm(fpre + f1) * g_c1[j]
           + sigm(fpre + f2) * g_c1[H + j];
  float hh = sigm(og) * ftanh(cc);
  g_root[j] = hh;
  g_root[H + j] = cc;
}

// ---------------- heads ----------------------------------------------------
__global__ __launch_bounds__(512) void k_head1(const float* __restrict__ ffnW,
                                               const float* __restrict__ ffnb) {
  __shared__ float hr[H];
  int j = threadIdx.x;
  hr[j] = g_root[j];
  __syncthreads();
  float acc = ffnb[j];
  #pragma unroll 8
  for (int m = 0; m < H; ++m) acc += hr[m] * ffnW[m * H + j];
  g_hf[j] = fmaxf(acc, 0.0f);
}

__global__ __launch_bounds__(64) void k_head2(const float* __restrict__ Wx,
                                              const float* __restrict__ lb) {
  int g = blockIdx.x * 64 + threadIdx.x;
  float acc = lb[g];
  #pragma unroll 8
  for (int m = 0; m < H; ++m) acc += g_hf[m] * Wx[m * 4 * H + g];
  g_gates[g] = acc;  // h_g starts at 0 so Wh term vanishes
}

// wave-parallel final heads: 8 waves, each wave owns outputs o, o+8, ...
// lane covers m = lane, lane+64, ... (16 elems), then 6-step shfl reduce.
__global__ __launch_bounds__(512) void k_head3(const float* __restrict__ vm,
    const float* __restrict__ hlW, const float* __restrict__ hlb,
    const float* __restrict__ intW, const float* __restrict__ intb,
    const float* __restrict__ actW, const float* __restrict__ actb,
    float* __restrict__ out) {
  __shared__ float feat[2 * H];
  int j = threadIdx.x;
  float ci = sigm(g_gates[j]) * ftanh(g_gates[2 * H + j]);
  float hg = sigm(g_gates[3 * H + j]) * ftanh(ci);
  feat[j] = g_hf[j];
  feat[H + j] = hg;
  __syncthreads();

  const int wv = threadIdx.x >> 6;
  const int lane = threadIdx.x & 63;
  for (int o = wv; o < 43; o += 8) {
    const float* Wc;
    int stride, colb;
    if (o < 2)       { Wc = hlW;  stride = 2;  colb = o; }
    else if (o < 7)  { Wc = intW; stride = 5;  colb = o - 2; }
    else             { Wc = actW; stride = 36; colb = o - 7; }
    float s = 0.f;
    #pragma unroll
    for (int q = 0; q < 16; ++q) {
      int m = lane + q * 64;
      s += feat[m] * Wc[(size_t)m * stride + colb];
    }
    #pragma unroll
    for (int d = 32; d >= 1; d >>= 1) s += __shfl_xor(s, d);
    if (lane == 0) {
      float res;
      if (o < 2)      res = s + hlb[o];
      else if (o < 7) res = s + intb[o - 2];
      else {
        int a = o - 7;
        float v = vm[a];
        res = __logf(v) + s * v + actb[a] * v;
      }
      out[o] = res;
    }
  }
}

extern "C" void kernel_launch(void* const* d_in, const int* in_sizes, int n_in,
                              void* d_out, int out_size, void* d_ws, size_t ws_size,
                              hipStream_t stream) {
  (void)in_sizes; (void)n_in; (void)d_ws; (void)ws_size; (void)out_size;
  const int* tokens   = (const int*)d_in[0];
  const float* vm     = (const float*)d_in[1];
  const float* Wiou_b = (const float*)d_in[2];
  const float* Uiou_b = (const float*)d_in[3];
  const float* biou_b = (const float*)d_in[4];
  const float* Wf_b   = (const float*)d_in[5];
  const float* Uf_b   = (const float*)d_in[6];
  const float* bf_b   = (const float*)d_in[7];
  const float* Wiou_t = (const float*)d_in[8];
  const float* Uiou_t = (const float*)d_in[9];
  const float* biou_t = (const float*)d_in[10];
  const float* Wf_t   = (const float*)d_in[11];
  const float* Uf_t   = (const float*)d_in[12];
  const float* bf_t   = (const float*)d_in[13];
  const float* ffnW   = (const float*)d_in[14];
  const float* ffnb   = (const float*)d_in[15];
  const float* lstmWx = (const float*)d_in[16];
  const float* lstmb  = (const float*)d_in[18];
  const float* hlW    = (const float*)d_in[19];
  const float* hlb    = (const float*)d_in[20];
  const float* intW   = (const float*)d_in[21];
  const float* intb   = (const float*)d_in[22];
  const float* actW   = (const float*)d_in[23];
  const float* actb   = (const float*)d_in[24];

  ushort_t* UiouT;  hipGetSymbolAddress((void**)&UiouT, HIP_SYMBOL(g_UiouT));
  ushort_t* UfT;    hipGetSymbolAddress((void**)&UfT, HIP_SYMBOL(g_UfT));
  ushort_t* UiouTt; hipGetSymbolAddress((void**)&UiouTt, HIP_SYMBOL(g_UiouTt));
  ushort_t* UfTt;   hipGetSymbolAddress((void**)&UfTt, HIP_SYMBOL(g_UfTt));

  // weight transpose+bf16 convert (every call; deterministic)
  k_transp<<<dim3(48, 32), 256, 0, stream>>>(Uiou_b, UiouT, 1024, 1536);
  k_transp<<<dim3(16, 32), 256, 0, stream>>>(Uf_b, UfT, 1024, 512);
  k_transp<<<dim3(48, 48), 256, 0, stream>>>(Uiou_t, UiouTt, 1536, 1536);
  k_transp<<<dim3(16, 48), 256, 0, stream>>>(Uf_t, UfTt, 1536, 512);

  k_leaf<<<NLEAF * H / 256, 256, 0, stream>>>(tokens, Wiou_b, biou_b);
  for (int lvl = 13; lvl >= 6; --lvl) {
    int gx = (1 << lvl) / 128; if (gx < 1) gx = 1;
    k_mfma_lvl<<<dim3(gx, 8), 256, 0, stream>>>(lvl, tokens, Wiou_b, biou_b,
                                                Wf_b, bf_b);
  }
  for (int lvl = 5; lvl >= 0; --lvl) {
    int n = 1 << lvl;
    k_sm_p1<<<dim3(10, 2, n), 256, 0, stream>>>(lvl);
    k_sm_p2<<<n, 512, 0, stream>>>(lvl, tokens, Wiou_b, biou_b, Wf_b, bf_b);
  }
  k_root_p1<<<dim3(12, 3), 256, 0, stream>>>();
  k_root_p2<<<1, 512, 0, stream>>>(tokens, Wiou_t, biou_t, Wf_t, bf_t);
  k_head1<<<1, 512, 0, stream>>>(ffnW, ffnb);
  k_head2<<<32, 64, 0, stream>>>(lstmWx, lstmb);
  k_head3<<<1, 512, 0, stream>>>(vm, hlW, hlb, intW, intb, actW, actb, (float*)d_out);
}

// Round 5
// 654.229 us; speedup vs baseline: 6.3951x; 1.0270x over previous
//
#include <hip/hip_runtime.h>
#include <hip/hip_bf16.h>
#include <math.h>

#define H 512
#define V 128
#define NLEAF 16384

typedef __attribute__((ext_vector_type(4))) float f32x4;
typedef __attribute__((ext_vector_type(8))) short s16x8;
typedef __attribute__((ext_vector_type(4))) unsigned short u16x4;
typedef unsigned short ushort_t;

// ---- static device scratch ----
__device__ ushort_t g_hb0[NLEAF * H];        // h bf16 (levels 14,12,...,0)
__device__ ushort_t g_hb1[(NLEAF / 2) * H];  // h bf16 (levels 13,11,...,1)
__device__ float    g_c0[NLEAF * H];         // c f32
__device__ float    g_c1[(NLEAF / 2) * H];
__device__ ushort_t g_UiouT[3 * H * 2 * H];  // [1536 cols][1024 k] bf16 (binary)
__device__ ushort_t g_UfT[H * 2 * H];        // [512 cols][1024 k] bf16 (f0|f1 halves)
__device__ ushort_t g_UiouTt[3 * H * 3 * H]; // [1536 cols][1536 k] bf16 (root)
__device__ ushort_t g_UfTt[H * 3 * H];       // [512 cols][1536 k] bf16 (f0|f1|f2 thirds)
__device__ float    g_rpart[3 * 3072];       // root k-chunk partials
__device__ float    g_root[2 * H];
__device__ float    g_hf[H];
__device__ float    g_gates[4 * H];

__device__ __forceinline__ float sigm(float x) { return 1.0f / (1.0f + __expf(-x)); }
__device__ __forceinline__ float ftanh(float x) {
  return 1.0f - 2.0f / (__expf(2.0f * x) + 1.0f);
}
__device__ __forceinline__ ushort_t f2bf(float x) {
  __hip_bfloat16 b = __float2bfloat16(x);
  return *reinterpret_cast<ushort_t*>(&b);
}
__device__ __forceinline__ float bf2f(ushort_t u) {
  union { unsigned int i; float f; } v; v.i = ((unsigned int)u) << 16; return v.f;
}
__device__ __forceinline__ void gload_lds16(const void* g, void* l) {
  __builtin_amdgcn_global_load_lds(
      (const __attribute__((address_space(1))) unsigned int*)g,
      (__attribute__((address_space(3))) unsigned int*)l, 16, 0, 0);
}

// ---------------- weight transpose+convert: dst[c][r] = bf16(src[r][c]) ----
__global__ __launch_bounds__(256) void k_transp(const float* __restrict__ src,
                                                ushort_t* __restrict__ dst,
                                                int R, int Cc) {
  __shared__ float t[32][33];
  int bc = blockIdx.x * 32, br = blockIdx.y * 32;
  int tx = threadIdx.x & 31, ty = threadIdx.x >> 5;  // 32 x 8
  for (int rr = ty; rr < 32; rr += 8)
    t[rr][tx] = src[(size_t)(br + rr) * Cc + bc + tx];
  __syncthreads();
  for (int rr = ty; rr < 32; rr += 8)
    dst[(size_t)(bc + rr) * R + br + tx] = f2bf(t[tx][rr]);
}

// ---------------- leaf level (lvl 14): hk = ck = 0, pure elementwise -------
// grid-stride, 4 j per thread, vectorized loads/stores
__global__ __launch_bounds__(256) void k_leaf(const int* __restrict__ tokens,
                                              const float* __restrict__ Wiou,
                                              const float* __restrict__ biou) {
  const int total = NLEAF * 128;                    // quads
  for (int q = blockIdx.x * 256 + threadIdx.x; q < total; q += gridDim.x * 256) {
    int i = q >> 7, jv = q & 127;                   // jv = j/4
    int tok = tokens[(NLEAF - 1) + i];
    const f32x4* Wr = (const f32x4*)(Wiou + (size_t)tok * 1536);
    const f32x4* bv = (const f32x4*)biou;
    f32x4 wi = Wr[jv] + bv[jv];
    f32x4 wo = Wr[128 + jv] + bv[128 + jv];
    f32x4 wu = Wr[256 + jv] + bv[256 + jv];
    u16x4 hv; f32x4 cv;
    #pragma unroll
    for (int r = 0; r < 4; ++r) {
      float c = sigm(wi[r]) * ftanh(wu[r]);
      float h = sigm(wo[r]) * ftanh(c);
      cv[r] = c;
      hv[r] = f2bf(h);
    }
    *reinterpret_cast<u16x4*>(&g_hb0[(size_t)q * 4]) = hv;
    *reinterpret_cast<f32x4*>(&g_c0[(size_t)q * 4]) = cv;
  }
}

// ---------------- big levels (n >= 64): MFMA bf16 fused cell ---------------
// block 128 thr = 2 waves. Tile: 64 nodes x 64 j-cols x 5 gates.
// LDS 40KB: A[2][4 rt][1KB] @0, B[2][16 ct][1KB] @8192. 4 blocks/CU.
__global__ __launch_bounds__(128, 2) void k_mfma_lvl(int lvl,
    const int* __restrict__ tokens,
    const float* __restrict__ Wiou, const float* __restrict__ biou,
    const float* __restrict__ Wf, const float* __restrict__ bf) {
  const int n = 1 << lvl;
  const int node0 = n - 1;
  const int outp = lvl & 1;
  const ushort_t* __restrict__ hprev = outp ? g_hb0 : g_hb1;
  const float* __restrict__ cprev = outp ? g_c0 : g_c1;
  ushort_t* __restrict__ hout = outp ? g_hb1 : g_hb0;
  float* __restrict__ cout = outp ? g_c1 : g_c0;

  const int i0 = blockIdx.x * 64;
  const int j0 = blockIdx.y * 64;
  const int tid = threadIdx.x;
  const int lane = tid & 63;
  const int w = tid >> 6;        // wave 0..1

  __shared__ f32x4 smemv[2560];  // 40KB
  char* smem = (char*)smemv;

  // staging: 20 chunks of 1KB per buffer; wave w stages chunks w*10..w*10+9
  const char* gp[10];
  unsigned lb[10], lstr[10];
  {
    int kb = (lane >> 4) * 16;
    #pragma unroll
    for (int q = 0; q < 10; ++q) {
      int c = w * 10 + q;
      if (c < 4) {               // A chunk, row-tile c
        int row = i0 + c * 16 + (lane & 15);
        gp[q] = (const char*)hprev + (size_t)row * 2048 + kb;
        lb[q] = c * 1024u;
        lstr[q] = 4096u;
      } else {                   // B chunk, col-tile ct
        int ct = c - 4;
        int col = ct * 16 + (lane & 15);     // 0..255: [i|o|u|f] x 64
        int g = col >> 6, jj = j0 + (col & 63);
        const ushort_t* Ub = (g < 3) ? (g_UiouT + (size_t)(g * 512 + jj) * 1024)
                                     : (g_UfT + (size_t)jj * 1024);
        gp[q] = (const char*)Ub + kb;
        lb[q] = 8192u + ct * 1024u;
        lstr[q] = 16384u;
      }
    }
  }

#define STAGE(BUF)                                                     \
  {                                                                    \
    _Pragma("unroll")                                                  \
    for (int q = 0; q < 10; ++q) {                                     \
      gload_lds16(gp[q], smem + lb[q] + (unsigned)(BUF) * lstr[q]);    \
      gp[q] += 64;                                                     \
    }                                                                  \
  }

  f32x4 acc[4][10];   // per row-tile: [i0,i1, o0,o1, u0,u1, f0a,f0b, f1a,f1b]
  #pragma unroll
  for (int a = 0; a < 4; ++a)
    #pragma unroll
    for (int b = 0; b < 10; ++b) acc[a][b] = (f32x4){0.f, 0.f, 0.f, 0.f};

#define COMPUTE(FA)                                                          \
  {                                                                          \
    const char* ab = smem + buf * 4096 + lane * 16;                          \
    s16x8 a0 = *(const s16x8*)(ab);                                          \
    s16x8 a1 = *(const s16x8*)(ab + 1024);                                   \
    s16x8 a2 = *(const s16x8*)(ab + 2048);                                   \
    s16x8 a3 = *(const s16x8*)(ab + 3072);                                   \
    const char* bb = smem + 8192 + buf * 16384 + w * 2048 + lane * 16;       \
    s16x8 b0 = *(const s16x8*)(bb);                                          \
    s16x8 b1 = *(const s16x8*)(bb + 1024);                                   \
    s16x8 b2 = *(const s16x8*)(bb + 4096);                                   \
    s16x8 b3 = *(const s16x8*)(bb + 5120);                                   \
    s16x8 b4 = *(const s16x8*)(bb + 8192);                                   \
    s16x8 b5 = *(const s16x8*)(bb + 9216);                                   \
    s16x8 b6 = *(const s16x8*)(bb + 12288);                                  \
    s16x8 b7 = *(const s16x8*)(bb + 13312);                                  \
    s16x8 aa[4] = {a0, a1, a2, a3};                                          \
    _Pragma("unroll")                                                        \
    for (int rtl = 0; rtl < 4; ++rtl) {                                      \
      acc[rtl][0] = __builtin_amdgcn_mfma_f32_16x16x32_bf16(aa[rtl], b0, acc[rtl][0], 0, 0, 0); \
      acc[rtl][1] = __builtin_amdgcn_mfma_f32_16x16x32_bf16(aa[rtl], b1, acc[rtl][1], 0, 0, 0); \
      acc[rtl][2] = __builtin_amdgcn_mfma_f32_16x16x32_bf16(aa[rtl], b2, acc[rtl][2], 0, 0, 0); \
      acc[rtl][3] = __builtin_amdgcn_mfma_f32_16x16x32_bf16(aa[rtl], b3, acc[rtl][3], 0, 0, 0); \
      acc[rtl][4] = __builtin_amdgcn_mfma_f32_16x16x32_bf16(aa[rtl], b4, acc[rtl][4], 0, 0, 0); \
      acc[rtl][5] = __builtin_amdgcn_mfma_f32_16x16x32_bf16(aa[rtl], b5, acc[rtl][5], 0, 0, 0); \
      acc[rtl][FA] = __builtin_amdgcn_mfma_f32_16x16x32_bf16(aa[rtl], b6, acc[rtl][FA], 0, 0, 0); \
      acc[rtl][FA + 1] = __builtin_amdgcn_mfma_f32_16x16x32_bf16(aa[rtl], b7, acc[rtl][FA + 1], 0, 0, 0); \
    }                                                                        \
  }

  STAGE(0);
  __syncthreads();
  int buf = 0;
  // k-halves split so f-accumulator indices stay compile-time (rule #20)
  for (int kt = 0; kt < 16; ++kt) {
    STAGE(buf ^ 1);
    COMPUTE(6);
    __syncthreads();
    buf ^= 1;
  }
  for (int kt = 16; kt < 32; ++kt) {
    if (kt < 31) STAGE(buf ^ 1);
    COMPUTE(8);
    __syncthreads();
    buf ^= 1;
  }
#undef COMPUTE
#undef STAGE

  // ---- fused epilogue (f32): C/D layout col=lane&15, row=(lane>>4)*4+reg --
  const int node_c = lane >> 4;
  const int jl = lane & 15;
  #pragma unroll
  for (int t = 0; t < 2; ++t) {
    const int j = j0 + w * 32 + t * 16 + jl;
    const float bi = biou[j], bo = biou[512 + j], bu = biou[1024 + j], bfv = bf[j];
    #pragma unroll
    for (int rtl = 0; rtl < 4; ++rtl) {
      f32x4 vi = acc[rtl][0 + t], vo = acc[rtl][2 + t], vu = acc[rtl][4 + t],
            v0 = acc[rtl][6 + t], v1 = acc[rtl][8 + t];
      const int ib = i0 + rtl * 16 + node_c * 4;
      #pragma unroll
      for (int r = 0; r < 4; ++r) {
        int i = ib + r;
        int tok = tokens[node0 + i];
        const float* Wr = Wiou + (size_t)tok * 1536;
        float fpre = Wf[(size_t)tok * 512 + j] + bfv;
        float ig = vi[r] + Wr[j] + bi;
        float og = vo[r] + Wr[512 + j] + bo;
        float ug = vu[r] + Wr[1024 + j] + bu;
        float cc = sigm(ig) * ftanh(ug)
                 + sigm(fpre + v0[r]) * cprev[(size_t)(2 * i) * 512 + j]
                 + sigm(fpre + v1[r]) * cprev[(size_t)(2 * i + 1) * 512 + j];
        float hh = sigm(og) * ftanh(cc);
        hout[(size_t)i * 512 + j] = f2bf(hh);
        cout[(size_t)i * 512 + j] = cc;
      }
    }
  }
}

// ------------- small levels (n <= 32): single fused kernel -----------------
// grid (8 jb, n), 256 thr. thread t: gate g=t>>6, col jj=j0+(t&63);
// full-1024k dot (f gate keeps the two k-half partials); LDS exchange;
// threads 0..63 run the cell epilogue.
__global__ __launch_bounds__(256) void k_small(int lvl,
    const int* __restrict__ tokens,
    const float* __restrict__ Wiou, const float* __restrict__ biou,
    const float* __restrict__ Wf, const float* __restrict__ bf) {
  const int n = 1 << lvl;
  const int node0 = n - 1;
  const int outp = lvl & 1;
  const ushort_t* __restrict__ hprev = outp ? g_hb0 : g_hb1;
  const float* __restrict__ cprev = outp ? g_c0 : g_c1;
  ushort_t* __restrict__ hout = outp ? g_hb1 : g_hb0;
  float* __restrict__ cout = outp ? g_c1 : g_c0;

  const int i = blockIdx.y;
  const int j0 = blockIdx.x * 64;
  const int tid = threadIdx.x;
  const int g = tid >> 6;
  const int jc = tid & 63;
  const int jj = j0 + jc;

  __shared__ float hl[1024];
  __shared__ float exch[5][64];
  for (int t = tid; t < 1024; t += 256) hl[t] = bf2f(hprev[(size_t)i * 1024 + t]);
  __syncthreads();

  const ushort_t* col = (g < 3) ? (g_UiouT + (size_t)(g * 512 + jj) * 1024)
                                : (g_UfT + (size_t)jj * 1024);
  float a0 = 0.f, a1 = 0.f;
  #pragma unroll 4
  for (int k0 = 0; k0 < 512; k0 += 8) {
    s16x8 wv = *(const s16x8*)(col + k0);
    #pragma unroll
    for (int r = 0; r < 8; ++r) a0 += hl[k0 + r] * bf2f((ushort_t)wv[r]);
  }
  #pragma unroll 4
  for (int k0 = 512; k0 < 1024; k0 += 8) {
    s16x8 wv = *(const s16x8*)(col + k0);
    #pragma unroll
    for (int r = 0; r < 8; ++r) a1 += hl[k0 + r] * bf2f((ushort_t)wv[r]);
  }
  if (g < 3) exch[g][jc] = a0 + a1;
  else { exch[3][jc] = a0; exch[4][jc] = a1; }
  __syncthreads();

  if (tid < 64) {
    int j = j0 + tid;
    float ai = exch[0][tid], ao = exch[1][tid], au = exch[2][tid];
    float af0 = exch[3][tid], af1 = exch[4][tid];
    int tok = tokens[node0 + i];
    const float* Wr = Wiou + (size_t)tok * 1536;
    float fpre = Wf[(size_t)tok * 512 + j] + bf[j];
    float ig = ai + Wr[j] + biou[j];
    float og = ao + Wr[512 + j] + biou[512 + j];
    float ug = au + Wr[1024 + j] + biou[1024 + j];
    float cc = sigm(ig) * ftanh(ug)
             + sigm(fpre + af0) * cprev[(size_t)(2 * i) * 512 + j]
             + sigm(fpre + af1) * cprev[(size_t)(2 * i + 1) * 512 + j];
    float hh = sigm(og) * ftanh(cc);
    hout[(size_t)i * 512 + j] = f2bf(hh);
    cout[(size_t)i * 512 + j] = cc;
  }
}

// ---------------- root ternary cell: 2-phase k-split -----------------------
__global__ __launch_bounds__(256) void k_root_p1() {
  const int by = blockIdx.y;
  const int tid = threadIdx.x;
  const int c = blockIdx.x * 256 + tid;      // 0..3071

  __shared__ float hl[512];
  {
    int m0 = by * 512;
    #pragma unroll
    for (int q = 0; q < 2; ++q) {
      int t = tid + q * 256, m = m0 + t;
      hl[t] = (m < 512) ? bf2f(g_hb0[m]) : bf2f(g_hb1[m - 512]);
    }
  }
  __syncthreads();

  float acc = 0.f;
  const ushort_t* col = nullptr;
  if (c < 1536) {
    col = g_UiouTt + (size_t)c * 1536 + by * 512;
  } else {
    int v = c - 1536;
    if ((v >> 9) == by) col = g_UfTt + (size_t)(v & 511) * 1536 + by * 512;
  }
  if (col) {
    #pragma unroll 4
    for (int k0 = 0; k0 < 512; k0 += 8) {
      s16x8 wv = *(const s16x8*)(col + k0);
      #pragma unroll
      for (int r = 0; r < 8; ++r) acc += hl[k0 + r] * bf2f((ushort_t)wv[r]);
    }
  }
  g_rpart[(size_t)by * 3072 + c] = acc;
}

__global__ __launch_bounds__(512) void k_root_p2(const int* __restrict__ tokens,
    const float* __restrict__ Wiou_t, const float* __restrict__ biou_t,
    const float* __restrict__ Wf_t, const float* __restrict__ bf_t) {
  const int j = threadIdx.x;
  float ai = g_rpart[j] + g_rpart[3072 + j] + g_rpart[6144 + j];
  float ao = g_rpart[512 + j] + g_rpart[3072 + 512 + j] + g_rpart[6144 + 512 + j];
  float au = g_rpart[1024 + j] + g_rpart[3072 + 1024 + j] + g_rpart[6144 + 1024 + j];
  float f0 = g_rpart[1536 + j] + g_rpart[3072 + 1536 + j] + g_rpart[6144 + 1536 + j];
  float f1 = g_rpart[2048 + j] + g_rpart[3072 + 2048 + j] + g_rpart[6144 + 2048 + j];
  float f2 = g_rpart[2560 + j] + g_rpart[3072 + 2560 + j] + g_rpart[6144 + 2560 + j];

  int tok = tokens[0];
  float fpre = Wf_t[(size_t)tok * H + j] + bf_t[j];
  float ig = ai + Wiou_t[(size_t)tok * 3 * H + j] + biou_t[j];
  float og = ao + Wiou_t[(size_t)tok * 3 * H + H + j] + biou_t[H + j];
  float ug = au + Wiou_t[(size_t)tok * 3 * H + 2 * H + j] + biou_t[2 * H + j];
  float cc = sigm(ig) * ftanh(ug)
           + sigm(fpre + f0) * g_c0[j]
           + sigm(fpre + f1) * g_c1[j]
           + sigm(fpre + f2) * g_c1[H + j];
  float hh = sigm(og) * ftanh(cc);
  g_root[j] = hh;
  g_root[H + j] = cc;
}

// ---------------- heads ----------------------------------------------------
__global__ __launch_bounds__(512) void k_head1(const float* __restrict__ ffnW,
                                               const float* __restrict__ ffnb) {
  __shared__ float hr[H];
  int j = threadIdx.x;
  hr[j] = g_root[j];
  __syncthreads();
  float acc = ffnb[j];
  #pragma unroll 8
  for (int m = 0; m < H; ++m) acc += hr[m] * ffnW[m * H + j];
  g_hf[j] = fmaxf(acc, 0.0f);
}

__global__ __launch_bounds__(64) void k_head2(const float* __restrict__ Wx,
                                              const float* __restrict__ lb) {
  int g = blockIdx.x * 64 + threadIdx.x;
  float acc = lb[g];
  #pragma unroll 8
  for (int m = 0; m < H; ++m) acc += g_hf[m] * Wx[m * 4 * H + g];
  g_gates[g] = acc;  // h_g starts at 0 so Wh term vanishes
}

// wave-parallel final heads: 8 waves, each wave owns outputs o, o+8, ...
__global__ __launch_bounds__(512) void k_head3(const float* __restrict__ vm,
    const float* __restrict__ hlW, const float* __restrict__ hlb,
    const float* __restrict__ intW, const float* __restrict__ intb,
    const float* __restrict__ actW, const float* __restrict__ actb,
    float* __restrict__ out) {
  __shared__ float feat[2 * H];
  int j = threadIdx.x;
  float ci = sigm(g_gates[j]) * ftanh(g_gates[2 * H + j]);
  float hg = sigm(g_gates[3 * H + j]) * ftanh(ci);
  feat[j] = g_hf[j];
  feat[H + j] = hg;
  __syncthreads();

  const int wv = threadIdx.x >> 6;
  const int lane = threadIdx.x & 63;
  for (int o = wv; o < 43; o += 8) {
    const float* Wc;
    int stride, colb;
    if (o < 2)       { Wc = hlW;  stride = 2;  colb = o; }
    else if (o < 7)  { Wc = intW; stride = 5;  colb = o - 2; }
    else             { Wc = actW; stride = 36; colb = o - 7; }
    float s = 0.f;
    #pragma unroll
    for (int q = 0; q < 16; ++q) {
      int m = lane + q * 64;
      s += feat[m] * Wc[(size_t)m * stride + colb];
    }
    #pragma unroll
    for (int d = 32; d >= 1; d >>= 1) s += __shfl_xor(s, d);
    if (lane == 0) {
      float res;
      if (o < 2)      res = s + hlb[o];
      else if (o < 7) res = s + intb[o - 2];
      else {
        int a = o - 7;
        float v = vm[a];
        res = __logf(v) + s * v + actb[a] * v;
      }
      out[o] = res;
    }
  }
}

extern "C" void kernel_launch(void* const* d_in, const int* in_sizes, int n_in,
                              void* d_out, int out_size, void* d_ws, size_t ws_size,
                              hipStream_t stream) {
  (void)in_sizes; (void)n_in; (void)d_ws; (void)ws_size; (void)out_size;
  const int* tokens   = (const int*)d_in[0];
  const float* vm     = (const float*)d_in[1];
  const float* Wiou_b = (const float*)d_in[2];
  const float* Uiou_b = (const float*)d_in[3];
  const float* biou_b = (const float*)d_in[4];
  const float* Wf_b   = (const float*)d_in[5];
  const float* Uf_b   = (const float*)d_in[6];
  const float* bf_b   = (const float*)d_in[7];
  const float* Wiou_t = (const float*)d_in[8];
  const float* Uiou_t = (const float*)d_in[9];
  const float* biou_t = (const float*)d_in[10];
  const float* Wf_t   = (const float*)d_in[11];
  const float* Uf_t   = (const float*)d_in[12];
  const float* bf_t   = (const float*)d_in[13];
  const float* ffnW   = (const float*)d_in[14];
  const float* ffnb   = (const float*)d_in[15];
  const float* lstmWx = (const float*)d_in[16];
  const float* lstmb  = (const float*)d_in[18];
  const float* hlW    = (const float*)d_in[19];
  const float* hlb    = (const float*)d_in[20];
  const float* intW   = (const float*)d_in[21];
  const float* intb   = (const float*)d_in[22];
  const float* actW   = (const float*)d_in[23];
  const float* actb   = (const float*)d_in[24];

  ushort_t* UiouT;  hipGetSymbolAddress((void**)&UiouT, HIP_SYMBOL(g_UiouT));
  ushort_t* UfT;    hipGetSymbolAddress((void**)&UfT, HIP_SYMBOL(g_UfT));
  ushort_t* UiouTt; hipGetSymbolAddress((void**)&UiouTt, HIP_SYMBOL(g_UiouTt));
  ushort_t* UfTt;   hipGetSymbolAddress((void**)&UfTt, HIP_SYMBOL(g_UfTt));

  // weight transpose+bf16 convert (every call; deterministic)
  k_transp<<<dim3(48, 32), 256, 0, stream>>>(Uiou_b, UiouT, 1024, 1536);
  k_transp<<<dim3(16, 32), 256, 0, stream>>>(Uf_b, UfT, 1024, 512);
  k_transp<<<dim3(48, 48), 256, 0, stream>>>(Uiou_t, UiouTt, 1536, 1536);
  k_transp<<<dim3(16, 48), 256, 0, stream>>>(Uf_t, UfTt, 1536, 512);

  k_leaf<<<2048, 256, 0, stream>>>(tokens, Wiou_b, biou_b);
  for (int lvl = 13; lvl >= 6; --lvl) {
    int gx = (1 << lvl) / 64;
    k_mfma_lvl<<<dim3(gx, 8), 128, 0, stream>>>(lvl, tokens, Wiou_b, biou_b,
                                                Wf_b, bf_b);
  }
  for (int lvl = 5; lvl >= 0; --lvl) {
    int n = 1 << lvl;
    k_small<<<dim3(8, n), 256, 0, stream>>>(lvl, tokens, Wiou_b, biou_b,
                                            Wf_b, bf_b);
  }
  k_root_p1<<<dim3(12, 3), 256, 0, stream>>>();
  k_root_p2<<<1, 512, 0, stream>>>(tokens, Wiou_t, biou_t, Wf_t, bf_t);
  k_head1<<<1, 512, 0, stream>>>(ffnW, ffnb);
  k_head2<<<32, 64, 0, stream>>>(lstmWx, lstmb);
  k_head3<<<1, 512, 0, stream>>>(vm, hlW, hlb, intW, intb, actW, actb, (float*)d_out);
}